// Round 1
// baseline (2328.669 us; speedup 1.0000x reference)
//
#include <hip/hip_runtime.h>

#define N_NODES 100000
#define N_EDGES 800000
#define IN_F 64
#define HID 128
#define OUT_F 64
#define BN_EPS 1e-5f

// ---------------------------------------------------------------------------
// scatter1: for each edge e: agg[dst] += x[src] (64 feats), deg[dst] += 1
// 16 lanes per edge, 4 floats (one float4 gather) per lane.
// ---------------------------------------------------------------------------
__global__ __launch_bounds__(256) void scatter1_kernel(
    const float* __restrict__ x, const int* __restrict__ esrc,
    const int* __restrict__ edst, float* __restrict__ agg,
    float* __restrict__ deg) {
  int t = blockIdx.x * 256 + threadIdx.x;
  int e = t >> 4;
  int j = t & 15;
  if (e >= N_EDGES) return;
  int s = esrc[e];
  int d = edst[e];
  const float4 v = *reinterpret_cast<const float4*>(x + (size_t)s * IN_F + j * 4);
  float* a = agg + (size_t)d * IN_F + j * 4;
  unsafeAtomicAdd(a + 0, v.x);
  unsafeAtomicAdd(a + 1, v.y);
  unsafeAtomicAdd(a + 2, v.z);
  unsafeAtomicAdd(a + 3, v.w);
  if (j == 0) unsafeAtomicAdd(deg + d, 1.0f);
}

// ---------------------------------------------------------------------------
// gemm1: h[n,0:128] = x[n,:]@Ws + (agg[n,:]/max(deg,1))@Wn + b
// block = 256 thr = 4 waves; wave w owns features w*32..w*32+32; lane = node.
// W reads are wave-uniform -> LDS broadcast (no bank conflicts).
// ---------------------------------------------------------------------------
__global__ __launch_bounds__(256) void gemm1_kernel(
    const float* __restrict__ x, const float* __restrict__ agg,
    const float* __restrict__ deg, const float* __restrict__ Ws,
    const float* __restrict__ Wn, const float* __restrict__ b,
    float* __restrict__ h) {
  __shared__ float ws[IN_F * HID];
  __shared__ float wn[IN_F * HID];
  __shared__ float bs[HID];
  int tid = threadIdx.x;
  for (int i = tid; i < IN_F * HID; i += 256) {
    ws[i] = Ws[i];
    wn[i] = Wn[i];
  }
  if (tid < HID) bs[tid] = b[tid];
  __syncthreads();

  int wave = tid >> 6;
  int lane = tid & 63;
  int n = blockIdx.x * 64 + lane;
  if (n >= N_NODES) return;
  int f0 = wave * 32;

  float rd = deg[n];
  rd = 1.0f / fmaxf(rd, 1.0f);

  float acc[32];
#pragma unroll
  for (int i = 0; i < 32; ++i) acc[i] = bs[f0 + i];

  const float* xr = x + (size_t)n * IN_F;
  const float* ar = agg + (size_t)n * IN_F;

  for (int k4 = 0; k4 < IN_F / 4; ++k4) {
    float4 xv = *reinterpret_cast<const float4*>(xr + k4 * 4);
    float4 av = *reinterpret_cast<const float4*>(ar + k4 * 4);
    av.x *= rd; av.y *= rd; av.z *= rd; av.w *= rd;
    const float* wsk = ws + (k4 * 4) * HID + f0;
    const float* wnk = wn + (k4 * 4) * HID + f0;
#pragma unroll
    for (int i = 0; i < 32; ++i) {
      acc[i] += xv.x * wsk[i] + av.x * wnk[i];
      acc[i] += xv.y * wsk[HID + i] + av.y * wnk[HID + i];
      acc[i] += xv.z * wsk[2 * HID + i] + av.z * wnk[2 * HID + i];
      acc[i] += xv.w * wsk[3 * HID + i] + av.w * wnk[3 * HID + i];
    }
  }

  float* hr = h + (size_t)n * HID + f0;
#pragma unroll
  for (int i = 0; i < 32; ++i) hr[i] = acc[i];
}

// ---------------------------------------------------------------------------
// bnstats: per-feature sum and sum-of-squares over all nodes.
// thread f = tid&127 walks rows; two row-halves reduced in LDS, then atomics.
// ---------------------------------------------------------------------------
__global__ __launch_bounds__(256) void bnstats_kernel(
    const float* __restrict__ h, float* __restrict__ bnsum) {
  int f = threadIdx.x & 127;
  int half = threadIdx.x >> 7;
  int stride = gridDim.x * 2;
  float s = 0.f, q = 0.f;
  for (int r = blockIdx.x * 2 + half; r < N_NODES; r += stride) {
    float v = h[(size_t)r * HID + f];
    s += v;
    q += v * v;
  }
  __shared__ float ls[256];
  __shared__ float lq[256];
  ls[threadIdx.x] = s;
  lq[threadIdx.x] = q;
  __syncthreads();
  if (half == 0) {
    float st = ls[f] + ls[f + 128];
    float qt = lq[f] + lq[f + 128];
    unsafeAtomicAdd(bnsum + f, st);
    unsafeAtomicAdd(bnsum + 128 + f, qt);
  }
}

// ---------------------------------------------------------------------------
// bnfinal: scale = gamma*rsqrt(var+eps); shift = beta - mu*scale
// ---------------------------------------------------------------------------
__global__ void bnfinal_kernel(const float* __restrict__ bnsum,
                               const float* __restrict__ gamma,
                               const float* __restrict__ beta,
                               float* __restrict__ scale,
                               float* __restrict__ shift) {
  int f = threadIdx.x;
  if (f >= HID) return;
  const float invn = 1.0f / (float)N_NODES;
  float mu = bnsum[f] * invn;
  float var = bnsum[128 + f] * invn - mu * mu;
  float sc = gamma[f] * rsqrtf(var + BN_EPS);
  scale[f] = sc;
  shift[f] = beta[f] - mu * sc;
}

// ---------------------------------------------------------------------------
// scatter2: hb = relu(h*scale+shift) computed on the fly;
//           agg[dst] += hb[src] (128 feats). 32 lanes/edge, float4 each.
// ---------------------------------------------------------------------------
__global__ __launch_bounds__(256) void scatter2_kernel(
    const float* __restrict__ h, const int* __restrict__ esrc,
    const int* __restrict__ edst, const float* __restrict__ scale,
    const float* __restrict__ shift, float* __restrict__ agg) {
  int t = blockIdx.x * 256 + threadIdx.x;
  int e = t >> 5;
  int j = t & 31;
  if (e >= N_EDGES) return;
  int s = esrc[e];
  int d = edst[e];
  const float4 v = *reinterpret_cast<const float4*>(h + (size_t)s * HID + j * 4);
  const float4 sc = *reinterpret_cast<const float4*>(scale + j * 4);
  const float4 sh = *reinterpret_cast<const float4*>(shift + j * 4);
  float4 r;
  r.x = fmaxf(v.x * sc.x + sh.x, 0.f);
  r.y = fmaxf(v.y * sc.y + sh.y, 0.f);
  r.z = fmaxf(v.z * sc.z + sh.z, 0.f);
  r.w = fmaxf(v.w * sc.w + sh.w, 0.f);
  float* a = agg + (size_t)d * HID + j * 4;
  unsafeAtomicAdd(a + 0, r.x);
  unsafeAtomicAdd(a + 1, r.y);
  unsafeAtomicAdd(a + 2, r.z);
  unsafeAtomicAdd(a + 3, r.w);
}

// ---------------------------------------------------------------------------
// gemm2: out[n,0:64] = hb[n,:]@Ws + (agg[n,:]/max(deg,1))@Wn + b
// block = 256 thr = 4 waves; (wave&1) -> 32-feature group, (wave>>1) -> node
// half; lane = node. hb recomputed from h via scale/shift (+relu).
// ---------------------------------------------------------------------------
__global__ __launch_bounds__(256) void gemm2_kernel(
    const float* __restrict__ h, const float* __restrict__ agg,
    const float* __restrict__ deg, const float* __restrict__ scale,
    const float* __restrict__ shift, const float* __restrict__ Ws,
    const float* __restrict__ Wn, const float* __restrict__ b,
    float* __restrict__ out) {
  __shared__ float ws[HID * OUT_F];
  __shared__ float wn[HID * OUT_F];
  __shared__ float scs[HID];
  __shared__ float shs[HID];
  __shared__ float bs[OUT_F];
  int tid = threadIdx.x;
  for (int i = tid; i < HID * OUT_F; i += 256) {
    ws[i] = Ws[i];
    wn[i] = Wn[i];
  }
  if (tid < HID) {
    scs[tid] = scale[tid];
    shs[tid] = shift[tid];
  }
  if (tid < OUT_F) bs[tid] = b[tid];
  __syncthreads();

  int wave = tid >> 6;
  int lane = tid & 63;
  int f0 = (wave & 1) * 32;
  int n = blockIdx.x * 128 + (wave >> 1) * 64 + lane;
  if (n >= N_NODES) return;

  float rd = deg[n];
  rd = 1.0f / fmaxf(rd, 1.0f);

  float acc[32];
#pragma unroll
  for (int i = 0; i < 32; ++i) acc[i] = bs[f0 + i];

  const float* hr = h + (size_t)n * HID;
  const float* ar = agg + (size_t)n * HID;

  for (int k4 = 0; k4 < HID / 4; ++k4) {
    float4 hv = *reinterpret_cast<const float4*>(hr + k4 * 4);
    float4 av = *reinterpret_cast<const float4*>(ar + k4 * 4);
    // BN + ReLU on the fly for the self term
    hv.x = fmaxf(hv.x * scs[k4 * 4 + 0] + shs[k4 * 4 + 0], 0.f);
    hv.y = fmaxf(hv.y * scs[k4 * 4 + 1] + shs[k4 * 4 + 1], 0.f);
    hv.z = fmaxf(hv.z * scs[k4 * 4 + 2] + shs[k4 * 4 + 2], 0.f);
    hv.w = fmaxf(hv.w * scs[k4 * 4 + 3] + shs[k4 * 4 + 3], 0.f);
    av.x *= rd; av.y *= rd; av.z *= rd; av.w *= rd;
    const float* wsk = ws + (k4 * 4) * OUT_F + f0;
    const float* wnk = wn + (k4 * 4) * OUT_F + f0;
#pragma unroll
    for (int i = 0; i < 32; ++i) {
      acc[i] += hv.x * wsk[i] + av.x * wnk[i];
      acc[i] += hv.y * wsk[OUT_F + i] + av.y * wnk[OUT_F + i];
      acc[i] += hv.z * wsk[2 * OUT_F + i] + av.z * wnk[2 * OUT_F + i];
      acc[i] += hv.w * wsk[3 * OUT_F + i] + av.w * wnk[3 * OUT_F + i];
    }
  }

  float* orow = out + (size_t)n * OUT_F + f0;
#pragma unroll
  for (int i = 0; i < 32; ++i) orow[i] = acc[i];
}

// ---------------------------------------------------------------------------
extern "C" void kernel_launch(void* const* d_in, const int* in_sizes, int n_in,
                              void* d_out, int out_size, void* d_ws,
                              size_t ws_size, hipStream_t stream) {
  const float* x = (const float*)d_in[0];
  const int* esrc = (const int*)d_in[1];
  const int* edst = (const int*)d_in[2];
  const float* Ws1 = (const float*)d_in[3];
  const float* Wn1 = (const float*)d_in[4];
  const float* b1 = (const float*)d_in[5];
  const float* gamma = (const float*)d_in[6];
  const float* beta = (const float*)d_in[7];
  const float* Ws2 = (const float*)d_in[8];
  const float* Wn2 = (const float*)d_in[9];
  const float* b2 = (const float*)d_in[10];

  float* ws = (float*)d_ws;
  float* bnsum = ws;                        // 256 floats
  float* bnscale = ws + 256;                // 128
  float* bnshift = ws + 384;                // 128
  float* deg = ws + 512;                    // N
  float* A = deg + N_NODES;                 // N*128 (agg1 uses N*64 of it)
  float* hpre = A + (size_t)N_NODES * HID;  // N*128

  // zero bnsum + scale/shift + deg + agg1 region in one shot
  hipMemsetAsync(d_ws, 0, (512 + (size_t)N_NODES * (1 + IN_F)) * sizeof(float),
                 stream);

  scatter1_kernel<<<(N_EDGES * 16 + 255) / 256, 256, 0, stream>>>(x, esrc, edst,
                                                                  A, deg);

  gemm1_kernel<<<(N_NODES + 63) / 64, 256, 0, stream>>>(x, A, deg, Ws1, Wn1,
                                                        b1, hpre);

  bnstats_kernel<<<1024, 256, 0, stream>>>(hpre, bnsum);
  bnfinal_kernel<<<1, 128, 0, stream>>>(bnsum, gamma, beta, bnscale, bnshift);

  // re-zero agg region for layer 2 (full N*128 now)
  hipMemsetAsync(A, 0, (size_t)N_NODES * HID * sizeof(float), stream);

  scatter2_kernel<<<(N_EDGES * 32 + 255) / 256, 256, 0, stream>>>(
      hpre, esrc, edst, bnscale, bnshift, A);

  gemm2_kernel<<<(N_NODES + 127) / 128, 256, 0, stream>>>(
      hpre, A, deg, bnscale, bnshift, Ws2, Wn2, b2, (float*)d_out);
}

// Round 4
// 565.162 us; speedup vs baseline: 4.1204x; 4.1204x over previous
//
#include <hip/hip_runtime.h>

#define N_NODES 100000
#define N_EDGES 800000
#define IN_F 64
#define HID 128
#define OUT_F 64
#define BN_EPS 1e-5f

// ---------------------------------------------------------------------------
// count: degi[dst]++ per edge (int atomics, cheap)
// ---------------------------------------------------------------------------
__global__ __launch_bounds__(256) void count_kernel(const int* __restrict__ edst,
                                                    int* __restrict__ degi) {
  int e = blockIdx.x * 256 + threadIdx.x;
  if (e >= N_EDGES) return;
  atomicAdd(degi + edst[e], 1);
}

// ---------------------------------------------------------------------------
// scan: exclusive prefix sum of degi -> rowstart[0..N], single 1024-thr block
// ---------------------------------------------------------------------------
__global__ __launch_bounds__(1024) void scan_kernel(const int* __restrict__ degi,
                                                    int* __restrict__ rowstart) {
  __shared__ int part[1024];
  int t = threadIdx.x;
  const int chunk = (N_NODES + 1023) / 1024;  // 98
  int lo = t * chunk;
  int hi = lo + chunk;
  if (hi > N_NODES) hi = N_NODES;
  int s = 0;
  for (int i = lo; i < hi; ++i) s += degi[i];
  part[t] = s;
  __syncthreads();
  for (int off = 1; off < 1024; off <<= 1) {
    int v = (t >= off) ? part[t - off] : 0;
    __syncthreads();
    part[t] += v;
    __syncthreads();
  }
  int running = part[t] - s;  // exclusive prefix of this thread's chunk
  for (int i = lo; i < hi; ++i) {
    rowstart[i] = running;
    running += degi[i];
  }
  if (t == 1023) rowstart[N_NODES] = part[1023];
}

// ---------------------------------------------------------------------------
// fill: csr[rowstart[dst] + cursor[dst]++] = src
// ---------------------------------------------------------------------------
__global__ __launch_bounds__(256) void fill_kernel(
    const int* __restrict__ esrc, const int* __restrict__ edst,
    const int* __restrict__ rowstart, int* __restrict__ cursor,
    int* __restrict__ csr) {
  int e = blockIdx.x * 256 + threadIdx.x;
  if (e >= N_EDGES) return;
  int d = edst[e];
  int pos = atomicAdd(cursor + d, 1);
  csr[rowstart[d] + pos] = esrc[e];
}

// ---------------------------------------------------------------------------
// agg: dst[n,0:64] (+)= mean over in-edges of feat[src,0:64]
// 16 lanes per node (one float4 chunk each); csr reads broadcast within group.
// ACC=true: accumulate into existing dst (used for out = s + mean(z)).
// ---------------------------------------------------------------------------
template <bool ACC>
__global__ __launch_bounds__(256) void agg_kernel(
    const float* __restrict__ feat, const int* __restrict__ rowstart,
    const int* __restrict__ csr, float* __restrict__ dst) {
  int n = blockIdx.x * 16 + (threadIdx.x >> 4);
  int j = threadIdx.x & 15;
  if (n >= N_NODES) return;
  int r0 = rowstart[n];
  int r1 = rowstart[n + 1];
  float4 acc = {0.f, 0.f, 0.f, 0.f};
  int i = r0;
  for (; i + 1 < r1; i += 2) {
    int s0 = csr[i];
    int s1 = csr[i + 1];
    float4 v0 = *reinterpret_cast<const float4*>(feat + (size_t)s0 * 64 + j * 4);
    float4 v1 = *reinterpret_cast<const float4*>(feat + (size_t)s1 * 64 + j * 4);
    acc.x += v0.x + v1.x;
    acc.y += v0.y + v1.y;
    acc.z += v0.z + v1.z;
    acc.w += v0.w + v1.w;
  }
  if (i < r1) {
    int s0 = csr[i];
    float4 v0 = *reinterpret_cast<const float4*>(feat + (size_t)s0 * 64 + j * 4);
    acc.x += v0.x;
    acc.y += v0.y;
    acc.z += v0.z;
    acc.w += v0.w;
  }
  int deg = r1 - r0;
  float rd = 1.0f / (float)(deg > 0 ? deg : 1);
  float* dp = dst + (size_t)n * 64 + j * 4;
  float4 o;
  if (ACC) {
    float4 prev = *reinterpret_cast<const float4*>(dp);
    o.x = prev.x + acc.x * rd;
    o.y = prev.y + acc.y * rd;
    o.z = prev.z + acc.z * rd;
    o.w = prev.w + acc.w * rd;
  } else {
    o.x = acc.x * rd;
    o.y = acc.y * rd;
    o.z = acc.z * rd;
    o.w = acc.w * rd;
  }
  *reinterpret_cast<float4*>(dp) = o;
}

// ---------------------------------------------------------------------------
// gemm1: h[n,0:128] = x[n,:]@Ws + aggx[n,:]@Wn + b   (aggx already the mean)
// 4 waves; wave owns 32 of 128 output feats; lane = node.
// ---------------------------------------------------------------------------
__global__ __launch_bounds__(256) void gemm1_kernel(
    const float* __restrict__ x, const float* __restrict__ aggx,
    const float* __restrict__ Ws, const float* __restrict__ Wn,
    const float* __restrict__ b, float* __restrict__ h) {
  __shared__ float ws[IN_F * HID];
  __shared__ float wn[IN_F * HID];
  __shared__ float bs[HID];
  int tid = threadIdx.x;
  for (int i = tid; i < IN_F * HID; i += 256) {
    ws[i] = Ws[i];
    wn[i] = Wn[i];
  }
  if (tid < HID) bs[tid] = b[tid];
  __syncthreads();

  int wave = tid >> 6;
  int lane = tid & 63;
  int n = blockIdx.x * 64 + lane;
  if (n >= N_NODES) return;
  int f0 = wave * 32;

  float acc[32];
#pragma unroll
  for (int i = 0; i < 32; ++i) acc[i] = bs[f0 + i];

  const float* xr = x + (size_t)n * IN_F;
  const float* ar = aggx + (size_t)n * IN_F;

  for (int k4 = 0; k4 < IN_F / 4; ++k4) {
    float4 xv = *reinterpret_cast<const float4*>(xr + k4 * 4);
    float4 av = *reinterpret_cast<const float4*>(ar + k4 * 4);
    const float* wsk = ws + (k4 * 4) * HID + f0;
    const float* wnk = wn + (k4 * 4) * HID + f0;
#pragma unroll
    for (int i = 0; i < 32; ++i) {
      acc[i] += xv.x * wsk[i] + av.x * wnk[i];
      acc[i] += xv.y * wsk[HID + i] + av.y * wnk[HID + i];
      acc[i] += xv.z * wsk[2 * HID + i] + av.z * wnk[2 * HID + i];
      acc[i] += xv.w * wsk[3 * HID + i] + av.w * wnk[3 * HID + i];
    }
  }

  float* hr = h + (size_t)n * HID + f0;
#pragma unroll
  for (int i = 0; i < 32; ++i) hr[i] = acc[i];
}

// ---------------------------------------------------------------------------
// bnstats: per-feature sum / sumsq over nodes
// ---------------------------------------------------------------------------
__global__ __launch_bounds__(256) void bnstats_kernel(
    const float* __restrict__ h, float* __restrict__ bnsum) {
  int f = threadIdx.x & 127;
  int half = threadIdx.x >> 7;
  int stride = gridDim.x * 2;
  float s = 0.f, q = 0.f;
  for (int r = blockIdx.x * 2 + half; r < N_NODES; r += stride) {
    float v = h[(size_t)r * HID + f];
    s += v;
    q += v * v;
  }
  __shared__ float ls[256];
  __shared__ float lq[256];
  ls[threadIdx.x] = s;
  lq[threadIdx.x] = q;
  __syncthreads();
  if (half == 0) {
    unsafeAtomicAdd(bnsum + f, ls[f] + ls[f + 128]);
    unsafeAtomicAdd(bnsum + 128 + f, lq[f] + lq[f + 128]);
  }
}

__global__ void bnfinal_kernel(const float* __restrict__ bnsum,
                               const float* __restrict__ gamma,
                               const float* __restrict__ beta,
                               float* __restrict__ scale,
                               float* __restrict__ shift) {
  int f = threadIdx.x;
  if (f >= HID) return;
  const float invn = 1.0f / (float)N_NODES;
  float mu = bnsum[f] * invn;
  float var = bnsum[128 + f] * invn - mu * mu;
  float sc = gamma[f] * rsqrtf(var + BN_EPS);
  scale[f] = sc;
  shift[f] = beta[f] - mu * sc;
}

// ---------------------------------------------------------------------------
// gemm2pre: hb = relu(bn(h)); z = hb@Wn2 (to z buf), s = hb@Ws2 + b2 (to out)
// 4 waves: waves 0-1 -> z feats 0-63, waves 2-3 -> s feats 0-63; lane = node.
// ---------------------------------------------------------------------------
__global__ __launch_bounds__(256) void gemm2pre_kernel(
    const float* __restrict__ h, const float* __restrict__ scale,
    const float* __restrict__ shift, const float* __restrict__ Wn,
    const float* __restrict__ Ws, const float* __restrict__ b,
    float* __restrict__ z, float* __restrict__ sout) {
  __shared__ float wn[HID * OUT_F];
  __shared__ float wsm[HID * OUT_F];
  __shared__ float scs[HID];
  __shared__ float shs[HID];
  __shared__ float bs[OUT_F];
  int tid = threadIdx.x;
  for (int i = tid; i < HID * OUT_F; i += 256) {
    wn[i] = Wn[i];
    wsm[i] = Ws[i];
  }
  if (tid < HID) {
    scs[tid] = scale[tid];
    shs[tid] = shift[tid];
  }
  if (tid < OUT_F) bs[tid] = b[tid];
  __syncthreads();

  int wave = tid >> 6;
  int lane = tid & 63;
  int n = blockIdx.x * 64 + lane;
  if (n >= N_NODES) return;
  int f0 = (wave & 1) * 32;
  bool self = wave >= 2;
  const float* W = self ? wsm : wn;

  float acc[32];
#pragma unroll
  for (int i = 0; i < 32; ++i) acc[i] = self ? bs[f0 + i] : 0.f;

  const float* hr = h + (size_t)n * HID;

  for (int k4 = 0; k4 < HID / 4; ++k4) {
    float4 hv = *reinterpret_cast<const float4*>(hr + k4 * 4);
    hv.x = fmaxf(hv.x * scs[k4 * 4 + 0] + shs[k4 * 4 + 0], 0.f);
    hv.y = fmaxf(hv.y * scs[k4 * 4 + 1] + shs[k4 * 4 + 1], 0.f);
    hv.z = fmaxf(hv.z * scs[k4 * 4 + 2] + shs[k4 * 4 + 2], 0.f);
    hv.w = fmaxf(hv.w * scs[k4 * 4 + 3] + shs[k4 * 4 + 3], 0.f);
    const float* wk = W + (k4 * 4) * OUT_F + f0;
#pragma unroll
    for (int i = 0; i < 32; ++i) {
      acc[i] += hv.x * wk[i];
      acc[i] += hv.y * wk[OUT_F + i];
      acc[i] += hv.z * wk[2 * OUT_F + i];
      acc[i] += hv.w * wk[3 * OUT_F + i];
    }
  }

  float* dp = (self ? sout : z) + (size_t)n * OUT_F + f0;
#pragma unroll
  for (int i = 0; i < 32; ++i) dp[i] = acc[i];
}

// ---------------------------------------------------------------------------
extern "C" void kernel_launch(void* const* d_in, const int* in_sizes, int n_in,
                              void* d_out, int out_size, void* d_ws,
                              size_t ws_size, hipStream_t stream) {
  const float* x = (const float*)d_in[0];
  const int* esrc = (const int*)d_in[1];
  const int* edst = (const int*)d_in[2];
  const float* Ws1 = (const float*)d_in[3];
  const float* Wn1 = (const float*)d_in[4];
  const float* b1 = (const float*)d_in[5];
  const float* gamma = (const float*)d_in[6];
  const float* beta = (const float*)d_in[7];
  const float* Ws2 = (const float*)d_in[8];
  const float* Wn2 = (const float*)d_in[9];
  const float* b2 = (const float*)d_in[10];
  float* out = (float*)d_out;

  float* ws = (float*)d_ws;
  float* bnsum = ws;                     // 256
  float* bnscale = ws + 256;             // 128
  float* bnshift = ws + 384;             // 128
  int* degi = (int*)(ws + 512);          // N
  int* cursor = degi + N_NODES;          // N
  int* rowstart = cursor + N_NODES;      // N+1
  int* csr = rowstart + N_NODES + 1;     // E
  float* aggz = (float*)(csr + N_EDGES); // N*64  (aggx for L1, then z for L2)
  float* h = aggz + (size_t)N_NODES * 64;// N*128

  // zero bnsum/scale/shift + degi + cursor
  hipMemsetAsync(d_ws, 0, (512 + 2 * (size_t)N_NODES) * sizeof(float), stream);

  const int egrid = (N_EDGES + 255) / 256;
  count_kernel<<<egrid, 256, 0, stream>>>(edst, degi);
  scan_kernel<<<1, 1024, 0, stream>>>(degi, rowstart);
  fill_kernel<<<egrid, 256, 0, stream>>>(esrc, edst, rowstart, cursor, csr);

  // layer 1: aggx = mean_in(x); h = x@Ws1 + aggx@Wn1 + b1
  agg_kernel<false><<<(N_NODES + 15) / 16, 256, 0, stream>>>(x, rowstart, csr,
                                                             aggz);
  gemm1_kernel<<<(N_NODES + 63) / 64, 256, 0, stream>>>(x, aggz, Ws1, Wn1, b1,
                                                        h);

  // batchnorm stats
  bnstats_kernel<<<1024, 256, 0, stream>>>(h, bnsum);
  bnfinal_kernel<<<1, 128, 0, stream>>>(bnsum, gamma, beta, bnscale, bnshift);

  // layer 2: z = relu(bn(h))@Wn2 ; out = relu(bn(h))@Ws2 + b2 ; out += mean(z)
  gemm2pre_kernel<<<(N_NODES + 63) / 64, 256, 0, stream>>>(
      h, bnscale, bnshift, Wn2, Ws2, b2, aggz, out);
  agg_kernel<true><<<(N_NODES + 15) / 16, 256, 0, stream>>>(aggz, rowstart, csr,
                                                            out);
}

// Round 5
// 422.917 us; speedup vs baseline: 5.5062x; 1.3363x over previous
//
#include <hip/hip_runtime.h>

#define N_NODES 100000
#define N_EDGES 800000
#define IN_F 64
#define HID 128
#define OUT_F 64
#define BN_EPS 1e-5f
#define SCAN_NBLK ((N_NODES + 255) / 256)  // 391

// ---------------------------------------------------------------------------
// count: degi[dst]++ per edge (int atomics, cheap)
// ---------------------------------------------------------------------------
__global__ __launch_bounds__(256) void count_kernel(const int* __restrict__ edst,
                                                    int* __restrict__ degi) {
  int e = blockIdx.x * 256 + threadIdx.x;
  if (e >= N_EDGES) return;
  atomicAdd(degi + edst[e], 1);
}

// ---------------------------------------------------------------------------
// blocksum: bsum[b] = sum of degi[b*256 .. b*256+255]
// ---------------------------------------------------------------------------
__global__ __launch_bounds__(256) void blocksum_kernel(
    const int* __restrict__ degi, int* __restrict__ bsum) {
  __shared__ int ls[256];
  int i = blockIdx.x * 256 + threadIdx.x;
  ls[threadIdx.x] = (i < N_NODES) ? degi[i] : 0;
  __syncthreads();
  for (int off = 128; off > 0; off >>= 1) {
    if (threadIdx.x < off) ls[threadIdx.x] += ls[threadIdx.x + off];
    __syncthreads();
  }
  if (threadIdx.x == 0) bsum[blockIdx.x] = ls[0];
}

// ---------------------------------------------------------------------------
// scanb: exclusive scan of bsum[0..SCAN_NBLK) -> boff; total -> rowstart[N]
// single block, 512 threads (SCAN_NBLK=391 <= 512)
// ---------------------------------------------------------------------------
__global__ __launch_bounds__(512) void scanb_kernel(
    const int* __restrict__ bsum, int* __restrict__ boff,
    int* __restrict__ rowstart) {
  __shared__ int ls[512];
  int t = threadIdx.x;
  int v = (t < SCAN_NBLK) ? bsum[t] : 0;
  ls[t] = v;
  __syncthreads();
  for (int off = 1; off < 512; off <<= 1) {
    int u = (t >= off) ? ls[t - off] : 0;
    __syncthreads();
    ls[t] += u;
    __syncthreads();
  }
  if (t < SCAN_NBLK) boff[t] = ls[t] - v;  // exclusive
  if (t == 511) rowstart[N_NODES] = ls[511];
}

// ---------------------------------------------------------------------------
// writerow: rowstart[i] = boff[blk] + exclusive_scan_in_block(degi)
// ---------------------------------------------------------------------------
__global__ __launch_bounds__(256) void writerow_kernel(
    const int* __restrict__ degi, const int* __restrict__ boff,
    int* __restrict__ rowstart) {
  __shared__ int ls[256];
  int i = blockIdx.x * 256 + threadIdx.x;
  int t = threadIdx.x;
  int v = (i < N_NODES) ? degi[i] : 0;
  ls[t] = v;
  __syncthreads();
  for (int off = 1; off < 256; off <<= 1) {
    int u = (t >= off) ? ls[t - off] : 0;
    __syncthreads();
    ls[t] += u;
    __syncthreads();
  }
  if (i < N_NODES) rowstart[i] = boff[blockIdx.x] + ls[t] - v;
}

// ---------------------------------------------------------------------------
// fill: csr[rowstart[dst] + cursor[dst]++] = src
// ---------------------------------------------------------------------------
__global__ __launch_bounds__(256) void fill_kernel(
    const int* __restrict__ esrc, const int* __restrict__ edst,
    const int* __restrict__ rowstart, int* __restrict__ cursor,
    int* __restrict__ csr) {
  int e = blockIdx.x * 256 + threadIdx.x;
  if (e >= N_EDGES) return;
  int d = edst[e];
  int pos = atomicAdd(cursor + d, 1);
  csr[rowstart[d] + pos] = esrc[e];
}

// ---------------------------------------------------------------------------
// agg: dst[n,0:64] (+)= mean over in-edges of feat[src,0:64]
// 16 lanes per node (one float4 chunk each); csr reads broadcast within group.
// ACC=true: accumulate into existing dst (used for out = s + mean(z)).
// ---------------------------------------------------------------------------
template <bool ACC>
__global__ __launch_bounds__(256) void agg_kernel(
    const float* __restrict__ feat, const int* __restrict__ rowstart,
    const int* __restrict__ csr, float* __restrict__ dst) {
  int n = blockIdx.x * 16 + (threadIdx.x >> 4);
  int j = threadIdx.x & 15;
  if (n >= N_NODES) return;
  int r0 = rowstart[n];
  int r1 = rowstart[n + 1];
  float4 acc = {0.f, 0.f, 0.f, 0.f};
  int i = r0;
  for (; i + 1 < r1; i += 2) {
    int s0 = csr[i];
    int s1 = csr[i + 1];
    float4 v0 = *reinterpret_cast<const float4*>(feat + (size_t)s0 * 64 + j * 4);
    float4 v1 = *reinterpret_cast<const float4*>(feat + (size_t)s1 * 64 + j * 4);
    acc.x += v0.x + v1.x;
    acc.y += v0.y + v1.y;
    acc.z += v0.z + v1.z;
    acc.w += v0.w + v1.w;
  }
  if (i < r1) {
    int s0 = csr[i];
    float4 v0 = *reinterpret_cast<const float4*>(feat + (size_t)s0 * 64 + j * 4);
    acc.x += v0.x;
    acc.y += v0.y;
    acc.z += v0.z;
    acc.w += v0.w;
  }
  int deg = r1 - r0;
  float rd = 1.0f / (float)(deg > 0 ? deg : 1);
  float* dp = dst + (size_t)n * 64 + j * 4;
  float4 o;
  if (ACC) {
    float4 prev = *reinterpret_cast<const float4*>(dp);
    o.x = prev.x + acc.x * rd;
    o.y = prev.y + acc.y * rd;
    o.z = prev.z + acc.z * rd;
    o.w = prev.w + acc.w * rd;
  } else {
    o.x = acc.x * rd;
    o.y = acc.y * rd;
    o.z = acc.z * rd;
    o.w = acc.w * rd;
  }
  *reinterpret_cast<float4*>(dp) = o;
}

// ---------------------------------------------------------------------------
// gemm1: h[n,0:128] = x[n,:]@Ws + aggx[n,:]@Wn + b   (aggx already the mean)
// 4 waves; wave owns 32 of 128 output feats; lane = node.
// ---------------------------------------------------------------------------
__global__ __launch_bounds__(256) void gemm1_kernel(
    const float* __restrict__ x, const float* __restrict__ aggx,
    const float* __restrict__ Ws, const float* __restrict__ Wn,
    const float* __restrict__ b, float* __restrict__ h) {
  __shared__ float ws[IN_F * HID];
  __shared__ float wn[IN_F * HID];
  __shared__ float bs[HID];
  int tid = threadIdx.x;
  for (int i = tid; i < IN_F * HID; i += 256) {
    ws[i] = Ws[i];
    wn[i] = Wn[i];
  }
  if (tid < HID) bs[tid] = b[tid];
  __syncthreads();

  int wave = tid >> 6;
  int lane = tid & 63;
  int n = blockIdx.x * 64 + lane;
  if (n >= N_NODES) return;
  int f0 = wave * 32;

  float acc[32];
#pragma unroll
  for (int i = 0; i < 32; ++i) acc[i] = bs[f0 + i];

  const float* xr = x + (size_t)n * IN_F;
  const float* ar = aggx + (size_t)n * IN_F;

  for (int k4 = 0; k4 < IN_F / 4; ++k4) {
    float4 xv = *reinterpret_cast<const float4*>(xr + k4 * 4);
    float4 av = *reinterpret_cast<const float4*>(ar + k4 * 4);
    const float* wsk = ws + (k4 * 4) * HID + f0;
    const float* wnk = wn + (k4 * 4) * HID + f0;
#pragma unroll
    for (int i = 0; i < 32; ++i) {
      acc[i] += xv.x * wsk[i] + av.x * wnk[i];
      acc[i] += xv.y * wsk[HID + i] + av.y * wnk[HID + i];
      acc[i] += xv.z * wsk[2 * HID + i] + av.z * wnk[2 * HID + i];
      acc[i] += xv.w * wsk[3 * HID + i] + av.w * wnk[3 * HID + i];
    }
  }

  float* hr = h + (size_t)n * HID + f0;
#pragma unroll
  for (int i = 0; i < 32; ++i) hr[i] = acc[i];
}

// ---------------------------------------------------------------------------
// bnstats: per-feature sum / sumsq over nodes
// ---------------------------------------------------------------------------
__global__ __launch_bounds__(256) void bnstats_kernel(
    const float* __restrict__ h, float* __restrict__ bnsum) {
  int f = threadIdx.x & 127;
  int half = threadIdx.x >> 7;
  int stride = gridDim.x * 2;
  float s = 0.f, q = 0.f;
  for (int r = blockIdx.x * 2 + half; r < N_NODES; r += stride) {
    float v = h[(size_t)r * HID + f];
    s += v;
    q += v * v;
  }
  __shared__ float ls[256];
  __shared__ float lq[256];
  ls[threadIdx.x] = s;
  lq[threadIdx.x] = q;
  __syncthreads();
  if (half == 0) {
    unsafeAtomicAdd(bnsum + f, ls[f] + ls[f + 128]);
    unsafeAtomicAdd(bnsum + 128 + f, lq[f] + lq[f + 128]);
  }
}

__global__ void bnfinal_kernel(const float* __restrict__ bnsum,
                               const float* __restrict__ gamma,
                               const float* __restrict__ beta,
                               float* __restrict__ scale,
                               float* __restrict__ shift) {
  int f = threadIdx.x;
  if (f >= HID) return;
  const float invn = 1.0f / (float)N_NODES;
  float mu = bnsum[f] * invn;
  float var = bnsum[128 + f] * invn - mu * mu;
  float sc = gamma[f] * rsqrtf(var + BN_EPS);
  scale[f] = sc;
  shift[f] = beta[f] - mu * sc;
}

// ---------------------------------------------------------------------------
// gemm2pre: hb = relu(bn(h)); z = hb@Wn2 (to z buf), s = hb@Ws2 + b2 (to out)
// 4 waves: waves 0-1 -> z feats 0-63, waves 2-3 -> s feats 0-63; lane = node.
// ---------------------------------------------------------------------------
__global__ __launch_bounds__(256) void gemm2pre_kernel(
    const float* __restrict__ h, const float* __restrict__ scale,
    const float* __restrict__ shift, const float* __restrict__ Wn,
    const float* __restrict__ Ws, const float* __restrict__ b,
    float* __restrict__ z, float* __restrict__ sout) {
  __shared__ float wn[HID * OUT_F];
  __shared__ float wsm[HID * OUT_F];
  __shared__ float scs[HID];
  __shared__ float shs[HID];
  __shared__ float bs[OUT_F];
  int tid = threadIdx.x;
  for (int i = tid; i < HID * OUT_F; i += 256) {
    wn[i] = Wn[i];
    wsm[i] = Ws[i];
  }
  if (tid < HID) {
    scs[tid] = scale[tid];
    shs[tid] = shift[tid];
  }
  if (tid < OUT_F) bs[tid] = b[tid];
  __syncthreads();

  int wave = tid >> 6;
  int lane = tid & 63;
  int n = blockIdx.x * 64 + lane;
  if (n >= N_NODES) return;
  int f0 = (wave & 1) * 32;
  bool self = wave >= 2;
  const float* W = self ? wsm : wn;

  float acc[32];
#pragma unroll
  for (int i = 0; i < 32; ++i) acc[i] = self ? bs[f0 + i] : 0.f;

  const float* hr = h + (size_t)n * HID;

  for (int k4 = 0; k4 < HID / 4; ++k4) {
    float4 hv = *reinterpret_cast<const float4*>(hr + k4 * 4);
    hv.x = fmaxf(hv.x * scs[k4 * 4 + 0] + shs[k4 * 4 + 0], 0.f);
    hv.y = fmaxf(hv.y * scs[k4 * 4 + 1] + shs[k4 * 4 + 1], 0.f);
    hv.z = fmaxf(hv.z * scs[k4 * 4 + 2] + shs[k4 * 4 + 2], 0.f);
    hv.w = fmaxf(hv.w * scs[k4 * 4 + 3] + shs[k4 * 4 + 3], 0.f);
    const float* wk = W + (k4 * 4) * OUT_F + f0;
#pragma unroll
    for (int i = 0; i < 32; ++i) {
      acc[i] += hv.x * wk[i];
      acc[i] += hv.y * wk[OUT_F + i];
      acc[i] += hv.z * wk[2 * OUT_F + i];
      acc[i] += hv.w * wk[3 * OUT_F + i];
    }
  }

  float* dp = (self ? sout : z) + (size_t)n * OUT_F + f0;
#pragma unroll
  for (int i = 0; i < 32; ++i) dp[i] = acc[i];
}

// ---------------------------------------------------------------------------
extern "C" void kernel_launch(void* const* d_in, const int* in_sizes, int n_in,
                              void* d_out, int out_size, void* d_ws,
                              size_t ws_size, hipStream_t stream) {
  const float* x = (const float*)d_in[0];
  const int* esrc = (const int*)d_in[1];
  const int* edst = (const int*)d_in[2];
  const float* Ws1 = (const float*)d_in[3];
  const float* Wn1 = (const float*)d_in[4];
  const float* b1 = (const float*)d_in[5];
  const float* gamma = (const float*)d_in[6];
  const float* beta = (const float*)d_in[7];
  const float* Ws2 = (const float*)d_in[8];
  const float* Wn2 = (const float*)d_in[9];
  const float* b2 = (const float*)d_in[10];
  float* out = (float*)d_out;

  float* ws = (float*)d_ws;
  float* bnsum = ws;                     // 256
  float* bnscale = ws + 256;             // 128
  float* bnshift = ws + 384;             // 128
  int* degi = (int*)(ws + 512);          // N
  int* cursor = degi + N_NODES;          // N
  int* rowstart = cursor + N_NODES;      // N+1
  int* bsum = rowstart + N_NODES + 1;    // SCAN_NBLK
  int* boff = bsum + SCAN_NBLK;          // SCAN_NBLK
  int* csr = boff + SCAN_NBLK;           // E
  float* aggz = (float*)(csr + N_EDGES); // N*64  (aggx for L1, then z for L2)
  float* h = aggz + (size_t)N_NODES * 64;// N*128

  // zero bnsum/scale/shift + degi + cursor
  hipMemsetAsync(d_ws, 0, (512 + 2 * (size_t)N_NODES) * sizeof(float), stream);

  const int egrid = (N_EDGES + 255) / 256;
  count_kernel<<<egrid, 256, 0, stream>>>(edst, degi);
  blocksum_kernel<<<SCAN_NBLK, 256, 0, stream>>>(degi, bsum);
  scanb_kernel<<<1, 512, 0, stream>>>(bsum, boff, rowstart);
  writerow_kernel<<<SCAN_NBLK, 256, 0, stream>>>(degi, boff, rowstart);
  fill_kernel<<<egrid, 256, 0, stream>>>(esrc, edst, rowstart, cursor, csr);

  // layer 1: aggx = mean_in(x); h = x@Ws1 + aggx@Wn1 + b1
  agg_kernel<false><<<(N_NODES + 15) / 16, 256, 0, stream>>>(x, rowstart, csr,
                                                             aggz);
  gemm1_kernel<<<(N_NODES + 63) / 64, 256, 0, stream>>>(x, aggz, Ws1, Wn1, b1,
                                                        h);

  // batchnorm stats
  bnstats_kernel<<<1024, 256, 0, stream>>>(h, bnsum);
  bnfinal_kernel<<<1, 128, 0, stream>>>(bnsum, gamma, beta, bnscale, bnshift);

  // layer 2: z = relu(bn(h))@Wn2 ; out = relu(bn(h))@Ws2 + b2 ; out += mean(z)
  gemm2pre_kernel<<<(N_NODES + 63) / 64, 256, 0, stream>>>(
      h, bnscale, bnshift, Wn2, Ws2, b2, aggz, out);
  agg_kernel<true><<<(N_NODES + 15) / 16, 256, 0, stream>>>(aggz, rowstart, csr,
                                                            out);
}

// Round 7
// 280.103 us; speedup vs baseline: 8.3136x; 1.5099x over previous
//
#include <hip/hip_runtime.h>

#define N_NODES 100000
#define N_EDGES 800000
#define IN_F 64
#define HID 128
#define OUT_F 64
#define BN_EPS 1e-5f
#define SCAN_NBLK ((N_NODES + 255) / 256)  // 391

typedef __attribute__((ext_vector_type(8))) short short8v;
typedef __attribute__((ext_vector_type(4))) float f32x4;

// fp32 -> bf16 round-to-nearest-even
static __device__ __forceinline__ unsigned short f2bf(float f) {
  unsigned u = __float_as_uint(f);
  return (unsigned short)((u + 0x7FFFu + ((u >> 16) & 1u)) >> 16);
}

// ---------------------------------------------------------------------------
// count: degi[dst]++ per edge (int atomics, cheap)
// ---------------------------------------------------------------------------
__global__ __launch_bounds__(256) void count_kernel(const int* __restrict__ edst,
                                                    int* __restrict__ degi) {
  int e = blockIdx.x * 256 + threadIdx.x;
  if (e >= N_EDGES) return;
  atomicAdd(degi + edst[e], 1);
}

// ---------------------------------------------------------------------------
// hierarchical scan: blocksum -> scanb -> writerow
// ---------------------------------------------------------------------------
__global__ __launch_bounds__(256) void blocksum_kernel(
    const int* __restrict__ degi, int* __restrict__ bsum) {
  __shared__ int ls[256];
  int i = blockIdx.x * 256 + threadIdx.x;
  ls[threadIdx.x] = (i < N_NODES) ? degi[i] : 0;
  __syncthreads();
  for (int off = 128; off > 0; off >>= 1) {
    if (threadIdx.x < off) ls[threadIdx.x] += ls[threadIdx.x + off];
    __syncthreads();
  }
  if (threadIdx.x == 0) bsum[blockIdx.x] = ls[0];
}

__global__ __launch_bounds__(512) void scanb_kernel(
    const int* __restrict__ bsum, int* __restrict__ boff,
    int* __restrict__ rowstart) {
  __shared__ int ls[512];
  int t = threadIdx.x;
  int v = (t < SCAN_NBLK) ? bsum[t] : 0;
  ls[t] = v;
  __syncthreads();
  for (int off = 1; off < 512; off <<= 1) {
    int u = (t >= off) ? ls[t - off] : 0;
    __syncthreads();
    ls[t] += u;
    __syncthreads();
  }
  if (t < SCAN_NBLK) boff[t] = ls[t] - v;  // exclusive
  if (t == 511) rowstart[N_NODES] = ls[511];
}

__global__ __launch_bounds__(256) void writerow_kernel(
    const int* __restrict__ degi, const int* __restrict__ boff,
    int* __restrict__ rowstart) {
  __shared__ int ls[256];
  int i = blockIdx.x * 256 + threadIdx.x;
  int t = threadIdx.x;
  int v = (i < N_NODES) ? degi[i] : 0;
  ls[t] = v;
  __syncthreads();
  for (int off = 1; off < 256; off <<= 1) {
    int u = (t >= off) ? ls[t - off] : 0;
    __syncthreads();
    ls[t] += u;
    __syncthreads();
  }
  if (i < N_NODES) rowstart[i] = boff[blockIdx.x] + ls[t] - v;
}

// ---------------------------------------------------------------------------
// fill: csr[rowstart[dst] + cursor[dst]++] = src
// ---------------------------------------------------------------------------
__global__ __launch_bounds__(256) void fill_kernel(
    const int* __restrict__ esrc, const int* __restrict__ edst,
    const int* __restrict__ rowstart, int* __restrict__ cursor,
    int* __restrict__ csr) {
  int e = blockIdx.x * 256 + threadIdx.x;
  if (e >= N_EDGES) return;
  int d = edst[e];
  int pos = atomicAdd(cursor + d, 1);
  csr[rowstart[d] + pos] = esrc[e];
}

// ---------------------------------------------------------------------------
// agg: dst[n,0:64] (+)= mean over in-edges of feat[src,0:64]
// ---------------------------------------------------------------------------
template <bool ACC>
__global__ __launch_bounds__(256) void agg_kernel(
    const float* __restrict__ feat, const int* __restrict__ rowstart,
    const int* __restrict__ csr, float* __restrict__ dst) {
  int n = blockIdx.x * 16 + (threadIdx.x >> 4);
  int j = threadIdx.x & 15;
  if (n >= N_NODES) return;
  int r0 = rowstart[n];
  int r1 = rowstart[n + 1];
  float4 acc = {0.f, 0.f, 0.f, 0.f};
  int i = r0;
  for (; i + 1 < r1; i += 2) {
    int s0 = csr[i];
    int s1 = csr[i + 1];
    float4 v0 = *reinterpret_cast<const float4*>(feat + (size_t)s0 * 64 + j * 4);
    float4 v1 = *reinterpret_cast<const float4*>(feat + (size_t)s1 * 64 + j * 4);
    acc.x += v0.x + v1.x;
    acc.y += v0.y + v1.y;
    acc.z += v0.z + v1.z;
    acc.w += v0.w + v1.w;
  }
  if (i < r1) {
    int s0 = csr[i];
    float4 v0 = *reinterpret_cast<const float4*>(feat + (size_t)s0 * 64 + j * 4);
    acc.x += v0.x;
    acc.y += v0.y;
    acc.z += v0.z;
    acc.w += v0.w;
  }
  int deg = r1 - r0;
  float rd = 1.0f / (float)(deg > 0 ? deg : 1);
  float* dp = dst + (size_t)n * 64 + j * 4;
  float4 o;
  if (ACC) {
    float4 prev = *reinterpret_cast<const float4*>(dp);
    o.x = prev.x + acc.x * rd;
    o.y = prev.y + acc.y * rd;
    o.z = prev.z + acc.z * rd;
    o.w = prev.w + acc.w * rd;
  } else {
    o.x = acc.x * rd;
    o.y = acc.y * rd;
    o.z = acc.z * rd;
    o.w = acc.w * rd;
  }
  *reinterpret_cast<float4*>(dp) = o;
}

// ---------------------------------------------------------------------------
// gemm1_mfma: h[N x 128] = [x | aggx] (N x 128) @ [Ws1 ; Wn1] (128 x 128) + b1
// bf16 MFMA 16x16x32. Block: 64 rows, 4 waves x 16 rows. W transposed +
// XOR-swizzled in LDS (bf16). A converted fp32->bf16 in flight.
// A frag: row = lane&15, k = (lane>>4)*8 + j. C/D: col = lane&15,
// row = (lane>>4)*4 + reg (m89-verified).
// ---------------------------------------------------------------------------
__global__ __launch_bounds__(256) void gemm1_mfma(
    const float* __restrict__ x, const float* __restrict__ aggx,
    const float* __restrict__ Ws, const float* __restrict__ Wn,
    const float* __restrict__ b, float* __restrict__ h) {
  __shared__ __align__(16) unsigned short wt[128 * 128];  // [col][k], swizzled
  __shared__ float bs[HID];
  int tid = threadIdx.x;
  for (int i = tid; i < 128 * 128; i += 256) {
    int k = i >> 7, j = i & 127;
    float v = (k < 64) ? Ws[k * HID + j] : Wn[(k - 64) * HID + j];
    int idx = (j << 7) | k;
    wt[idx ^ ((j & 15) << 3)] = f2bf(v);
  }
  if (tid < HID) bs[tid] = b[tid];
  __syncthreads();

  int wave = tid >> 6, lane = tid & 63;
  int m = lane & 15, kg = lane >> 4;
  int rbase = blockIdx.x * 64 + wave * 16;
  int rowa = rbase + m;
  if (rowa >= N_NODES) rowa = N_NODES - 1;  // clamp (stores guarded)

  short8v a[4];
#pragma unroll
  for (int kt = 0; kt < 4; ++kt) {
    int c0 = kt * 32 + kg * 8;
    const float* src = (c0 < 64) ? (x + (size_t)rowa * 64 + c0)
                                 : (aggx + (size_t)rowa * 64 + (c0 - 64));
    float4 lo = *reinterpret_cast<const float4*>(src);
    float4 hi = *reinterpret_cast<const float4*>(src + 4);
    short8v av;
    av[0] = (short)f2bf(lo.x); av[1] = (short)f2bf(lo.y);
    av[2] = (short)f2bf(lo.z); av[3] = (short)f2bf(lo.w);
    av[4] = (short)f2bf(hi.x); av[5] = (short)f2bf(hi.y);
    av[6] = (short)f2bf(hi.z); av[7] = (short)f2bf(hi.w);
    a[kt] = av;
  }

  f32x4 acc[8];
#pragma unroll
  for (int nt = 0; nt < 8; ++nt) acc[nt] = (f32x4){0.f, 0.f, 0.f, 0.f};

#pragma unroll
  for (int nt = 0; nt < 8; ++nt) {
    int col = nt * 16 + m;
    int base = col << 7;
    int sw = (col & 15) << 3;
#pragma unroll
    for (int kt = 0; kt < 4; ++kt) {
      int idx = (base | (kt * 32 + kg * 8)) ^ sw;
      short8v bf = *reinterpret_cast<const short8v*>(&wt[idx]);
      acc[nt] = __builtin_amdgcn_mfma_f32_16x16x32_bf16(a[kt], bf, acc[nt], 0, 0, 0);
    }
  }

#pragma unroll
  for (int nt = 0; nt < 8; ++nt) {
    int col = nt * 16 + m;
    float bias = bs[col];
#pragma unroll
    for (int r = 0; r < 4; ++r) {
      int rr = rbase + kg * 4 + r;
      if (rr < N_NODES) h[(size_t)rr * HID + col] = acc[nt][r] + bias;
    }
  }
}

// ---------------------------------------------------------------------------
// bnstats: per-feature sum / sumsq over nodes
// ---------------------------------------------------------------------------
__global__ __launch_bounds__(256) void bnstats_kernel(
    const float* __restrict__ h, float* __restrict__ bnsum) {
  int f = threadIdx.x & 127;
  int half = threadIdx.x >> 7;
  int stride = gridDim.x * 2;
  float s = 0.f, q = 0.f;
  for (int r = blockIdx.x * 2 + half; r < N_NODES; r += stride) {
    float v = h[(size_t)r * HID + f];
    s += v;
    q += v * v;
  }
  __shared__ float ls[256];
  __shared__ float lq[256];
  ls[threadIdx.x] = s;
  lq[threadIdx.x] = q;
  __syncthreads();
  if (half == 0) {
    unsafeAtomicAdd(bnsum + f, ls[f] + ls[f + 128]);
    unsafeAtomicAdd(bnsum + 128 + f, lq[f] + lq[f + 128]);
  }
}

__global__ void bnfinal_kernel(const float* __restrict__ bnsum,
                               const float* __restrict__ gamma,
                               const float* __restrict__ beta,
                               float* __restrict__ scale,
                               float* __restrict__ shift) {
  int f = threadIdx.x;
  if (f >= HID) return;
  const float invn = 1.0f / (float)N_NODES;
  float mu = bnsum[f] * invn;
  float var = bnsum[128 + f] * invn - mu * mu;
  float sc = gamma[f] * rsqrtf(var + BN_EPS);
  scale[f] = sc;
  shift[f] = beta[f] - mu * sc;
}

// ---------------------------------------------------------------------------
// gemm2_mfma: hb = relu(bn(h)); [z | s] (N x 128) = hb (N x 128) @
// [Wn2 | Ws2] (128 x 128). z -> zbuf, s + b2 -> out. BN+ReLU fused in A-load.
// ---------------------------------------------------------------------------
__global__ __launch_bounds__(256) void gemm2_mfma(
    const float* __restrict__ h, const float* __restrict__ scale,
    const float* __restrict__ shift, const float* __restrict__ Wn,
    const float* __restrict__ Ws, const float* __restrict__ b,
    float* __restrict__ z, float* __restrict__ out) {
  __shared__ __align__(16) unsigned short wt[128 * 128];  // [col][k], swizzled
  __shared__ float scs[HID];
  __shared__ float shs[HID];
  __shared__ float bz[OUT_F];
  int tid = threadIdx.x;
  for (int i = tid; i < 128 * 128; i += 256) {
    int k = i >> 7, j = i & 127;
    float v = (j < 64) ? Wn[k * OUT_F + j] : Ws[k * OUT_F + (j - 64)];
    int idx = (j << 7) | k;
    wt[idx ^ ((j & 15) << 3)] = f2bf(v);
  }
  if (tid < HID) {
    scs[tid] = scale[tid];
    shs[tid] = shift[tid];
  }
  if (tid < OUT_F) bz[tid] = b[tid];
  __syncthreads();

  int wave = tid >> 6, lane = tid & 63;
  int m = lane & 15, kg = lane >> 4;
  int rbase = blockIdx.x * 64 + wave * 16;
  int rowa = rbase + m;
  if (rowa >= N_NODES) rowa = N_NODES - 1;

  short8v a[4];
#pragma unroll
  for (int kt = 0; kt < 4; ++kt) {
    int c0 = kt * 32 + kg * 8;
    const float* src = h + (size_t)rowa * HID + c0;
    float4 lo = *reinterpret_cast<const float4*>(src);
    float4 hi = *reinterpret_cast<const float4*>(src + 4);
    float4 sc0 = *reinterpret_cast<const float4*>(&scs[c0]);
    float4 sc1 = *reinterpret_cast<const float4*>(&scs[c0 + 4]);
    float4 sh0 = *reinterpret_cast<const float4*>(&shs[c0]);
    float4 sh1 = *reinterpret_cast<const float4*>(&shs[c0 + 4]);
    short8v av;
    av[0] = (short)f2bf(fmaxf(lo.x * sc0.x + sh0.x, 0.f));
    av[1] = (short)f2bf(fmaxf(lo.y * sc0.y + sh0.y, 0.f));
    av[2] = (short)f2bf(fmaxf(lo.z * sc0.z + sh0.z, 0.f));
    av[3] = (short)f2bf(fmaxf(lo.w * sc0.w + sh0.w, 0.f));
    av[4] = (short)f2bf(fmaxf(hi.x * sc1.x + sh1.x, 0.f));
    av[5] = (short)f2bf(fmaxf(hi.y * sc1.y + sh1.y, 0.f));
    av[6] = (short)f2bf(fmaxf(hi.z * sc1.z + sh1.z, 0.f));
    av[7] = (short)f2bf(fmaxf(hi.w * sc1.w + sh1.w, 0.f));
    a[kt] = av;
  }

  f32x4 acc[8];
#pragma unroll
  for (int nt = 0; nt < 8; ++nt) acc[nt] = (f32x4){0.f, 0.f, 0.f, 0.f};

#pragma unroll
  for (int nt = 0; nt < 8; ++nt) {
    int col = nt * 16 + m;
    int base = col << 7;
    int sw = (col & 15) << 3;
#pragma unroll
    for (int kt = 0; kt < 4; ++kt) {
      int idx = (base | (kt * 32 + kg * 8)) ^ sw;
      short8v bf = *reinterpret_cast<const short8v*>(&wt[idx]);
      acc[nt] = __builtin_amdgcn_mfma_f32_16x16x32_bf16(a[kt], bf, acc[nt], 0, 0, 0);
    }
  }

#pragma unroll
  for (int nt = 0; nt < 8; ++nt) {
    int col = nt * 16 + m;
#pragma unroll
    for (int r = 0; r < 4; ++r) {
      int rr = rbase + kg * 4 + r;
      if (rr < N_NODES) {
        float v = acc[nt][r];
        if (col < 64)
          z[(size_t)rr * OUT_F + col] = v;
        else
          out[(size_t)rr * OUT_F + (col - 64)] = v + bz[col - 64];
      }
    }
  }
}

// ---------------------------------------------------------------------------
extern "C" void kernel_launch(void* const* d_in, const int* in_sizes, int n_in,
                              void* d_out, int out_size, void* d_ws,
                              size_t ws_size, hipStream_t stream) {
  const float* x = (const float*)d_in[0];
  const int* esrc = (const int*)d_in[1];
  const int* edst = (const int*)d_in[2];
  const float* Ws1 = (const float*)d_in[3];
  const float* Wn1 = (const float*)d_in[4];
  const float* b1 = (const float*)d_in[5];
  const float* gamma = (const float*)d_in[6];
  const float* beta = (const float*)d_in[7];
  const float* Ws2 = (const float*)d_in[8];
  const float* Wn2 = (const float*)d_in[9];
  const float* b2 = (const float*)d_in[10];
  float* out = (float*)d_out;

  float* ws = (float*)d_ws;
  float* bnsum = ws;                     // 256
  float* bnscale = ws + 256;             // 128
  float* bnshift = ws + 384;             // 128
  int* degi = (int*)(ws + 512);          // N
  int* cursor = degi + N_NODES;          // N
  int* rowstart = cursor + N_NODES;      // N+1
  int* bsum = rowstart + N_NODES + 1;    // SCAN_NBLK
  int* boff = bsum + SCAN_NBLK;          // SCAN_NBLK
  int* csr = boff + SCAN_NBLK;           // E
  float* aggz = (float*)(csr + N_EDGES); // N*64  (aggx for L1, then z for L2)
  float* h = aggz + (size_t)N_NODES * 64;// N*128

  // zero bnsum/scale/shift + degi + cursor
  hipMemsetAsync(d_ws, 0, (512 + 2 * (size_t)N_NODES) * sizeof(float), stream);

  const int egrid = (N_EDGES + 255) / 256;
  count_kernel<<<egrid, 256, 0, stream>>>(edst, degi);
  blocksum_kernel<<<SCAN_NBLK, 256, 0, stream>>>(degi, bsum);
  scanb_kernel<<<1, 512, 0, stream>>>(bsum, boff, rowstart);
  writerow_kernel<<<SCAN_NBLK, 256, 0, stream>>>(degi, boff, rowstart);
  fill_kernel<<<egrid, 256, 0, stream>>>(esrc, edst, rowstart, cursor, csr);

  const int ggrid = (N_NODES + 63) / 64;
  // layer 1: aggx = mean_in(x); h = [x|aggx] @ [Ws1;Wn1] + b1
  agg_kernel<false><<<(N_NODES + 15) / 16, 256, 0, stream>>>(x, rowstart, csr,
                                                             aggz);
  gemm1_mfma<<<ggrid, 256, 0, stream>>>(x, aggz, Ws1, Wn1, b1, h);

  // batchnorm stats
  bnstats_kernel<<<1024, 256, 0, stream>>>(h, bnsum);
  bnfinal_kernel<<<1, 128, 0, stream>>>(bnsum, gamma, beta, bnscale, bnshift);

  // layer 2: [z|s] = relu(bn(h)) @ [Wn2|Ws2]; out = s + b2; out += mean_in(z)
  gemm2_mfma<<<ggrid, 256, 0, stream>>>(h, bnscale, bnshift, Wn2, Ws2, b2,
                                        aggz, out);
  agg_kernel<true><<<(N_NODES + 15) / 16, 256, 0, stream>>>(aggz, rowstart, csr,
                                                            out);
}

// Round 8
// 245.907 us; speedup vs baseline: 9.4697x; 1.1391x over previous
//
#include <hip/hip_runtime.h>

#define N_NODES 100000
#define N_EDGES 800000
#define IN_F 64
#define HID 128
#define OUT_F 64
#define BN_EPS 1e-5f
#define SCAN_NBLK ((N_NODES + 255) / 256)  // 391

typedef __attribute__((ext_vector_type(8))) short short8v;
typedef __attribute__((ext_vector_type(4))) float f32x4;

// fp32 -> bf16 round-to-nearest-even
static __device__ __forceinline__ unsigned short f2bf(float f) {
  unsigned u = __float_as_uint(f);
  return (unsigned short)((u + 0x7FFFu + ((u >> 16) & 1u)) >> 16);
}

// ---------------------------------------------------------------------------
// pass1: pos16[e] = cursor[dst]++  (one atomic pass gives rank AND histogram)
// 4 edges per thread (int4 load, ushort4 store).
// ---------------------------------------------------------------------------
__global__ __launch_bounds__(256) void pass1_kernel(
    const int* __restrict__ edst, int* __restrict__ cursor,
    unsigned short* __restrict__ pos16) {
  int t = blockIdx.x * 256 + threadIdx.x;
  if (t >= N_EDGES / 4) return;
  int4 d = reinterpret_cast<const int4*>(edst)[t];
  ushort4 p;
  p.x = (unsigned short)atomicAdd(cursor + d.x, 1);
  p.y = (unsigned short)atomicAdd(cursor + d.y, 1);
  p.z = (unsigned short)atomicAdd(cursor + d.z, 1);
  p.w = (unsigned short)atomicAdd(cursor + d.w, 1);
  reinterpret_cast<ushort4*>(pos16)[t] = p;
}

// ---------------------------------------------------------------------------
// hierarchical scan over cursor (= degrees): blocksum -> scanb -> writerow
// ---------------------------------------------------------------------------
__global__ __launch_bounds__(256) void blocksum_kernel(
    const int* __restrict__ degi, int* __restrict__ bsum) {
  __shared__ int ls[256];
  int i = blockIdx.x * 256 + threadIdx.x;
  ls[threadIdx.x] = (i < N_NODES) ? degi[i] : 0;
  __syncthreads();
  for (int off = 128; off > 0; off >>= 1) {
    if (threadIdx.x < off) ls[threadIdx.x] += ls[threadIdx.x + off];
    __syncthreads();
  }
  if (threadIdx.x == 0) bsum[blockIdx.x] = ls[0];
}

__global__ __launch_bounds__(512) void scanb_kernel(
    const int* __restrict__ bsum, int* __restrict__ boff,
    int* __restrict__ rowstart) {
  __shared__ int ls[512];
  int t = threadIdx.x;
  int v = (t < SCAN_NBLK) ? bsum[t] : 0;
  ls[t] = v;
  __syncthreads();
  for (int off = 1; off < 512; off <<= 1) {
    int u = (t >= off) ? ls[t - off] : 0;
    __syncthreads();
    ls[t] += u;
    __syncthreads();
  }
  if (t < SCAN_NBLK) boff[t] = ls[t] - v;  // exclusive
  if (t == 511) rowstart[N_NODES] = ls[511];
}

__global__ __launch_bounds__(256) void writerow_kernel(
    const int* __restrict__ degi, const int* __restrict__ boff,
    int* __restrict__ rowstart) {
  __shared__ int ls[256];
  int i = blockIdx.x * 256 + threadIdx.x;
  int t = threadIdx.x;
  int v = (i < N_NODES) ? degi[i] : 0;
  ls[t] = v;
  __syncthreads();
  for (int off = 1; off < 256; off <<= 1) {
    int u = (t >= off) ? ls[t - off] : 0;
    __syncthreads();
    ls[t] += u;
    __syncthreads();
  }
  if (i < N_NODES) rowstart[i] = boff[blockIdx.x] + ls[t] - v;
}

// ---------------------------------------------------------------------------
// scatter: csr[rowstart[dst] + pos16[e]] = src   (pure stores, no atomics)
// ---------------------------------------------------------------------------
__global__ __launch_bounds__(256) void scatter_kernel(
    const int* __restrict__ esrc, const int* __restrict__ edst,
    const unsigned short* __restrict__ pos16,
    const int* __restrict__ rowstart, int* __restrict__ csr) {
  int t = blockIdx.x * 256 + threadIdx.x;
  if (t >= N_EDGES / 4) return;
  int4 s = reinterpret_cast<const int4*>(esrc)[t];
  int4 d = reinterpret_cast<const int4*>(edst)[t];
  ushort4 p = reinterpret_cast<const ushort4*>(pos16)[t];
  csr[rowstart[d.x] + p.x] = s.x;
  csr[rowstart[d.y] + p.y] = s.y;
  csr[rowstart[d.z] + p.z] = s.z;
  csr[rowstart[d.w] + p.w] = s.w;
}

// ---------------------------------------------------------------------------
// agg: dst[n,0:64] (+)= mean over in-edges of feat[src,0:64]
// ---------------------------------------------------------------------------
template <bool ACC>
__global__ __launch_bounds__(256) void agg_kernel(
    const float* __restrict__ feat, const int* __restrict__ rowstart,
    const int* __restrict__ csr, float* __restrict__ dst) {
  int n = blockIdx.x * 16 + (threadIdx.x >> 4);
  int j = threadIdx.x & 15;
  if (n >= N_NODES) return;
  int r0 = rowstart[n];
  int r1 = rowstart[n + 1];
  float4 acc = {0.f, 0.f, 0.f, 0.f};
  int i = r0;
  for (; i + 1 < r1; i += 2) {
    int s0 = csr[i];
    int s1 = csr[i + 1];
    float4 v0 = *reinterpret_cast<const float4*>(feat + (size_t)s0 * 64 + j * 4);
    float4 v1 = *reinterpret_cast<const float4*>(feat + (size_t)s1 * 64 + j * 4);
    acc.x += v0.x + v1.x;
    acc.y += v0.y + v1.y;
    acc.z += v0.z + v1.z;
    acc.w += v0.w + v1.w;
  }
  if (i < r1) {
    int s0 = csr[i];
    float4 v0 = *reinterpret_cast<const float4*>(feat + (size_t)s0 * 64 + j * 4);
    acc.x += v0.x;
    acc.y += v0.y;
    acc.z += v0.z;
    acc.w += v0.w;
  }
  int deg = r1 - r0;
  float rd = 1.0f / (float)(deg > 0 ? deg : 1);
  float* dp = dst + (size_t)n * 64 + j * 4;
  float4 o;
  if (ACC) {
    float4 prev = *reinterpret_cast<const float4*>(dp);
    o.x = prev.x + acc.x * rd;
    o.y = prev.y + acc.y * rd;
    o.z = prev.z + acc.z * rd;
    o.w = prev.w + acc.w * rd;
  } else {
    o.x = acc.x * rd;
    o.y = acc.y * rd;
    o.z = acc.z * rd;
    o.w = acc.w * rd;
  }
  *reinterpret_cast<float4*>(dp) = o;
}

// ---------------------------------------------------------------------------
// gemm1_mfma: h[N x 128] = [x | aggx] (N x 128) @ [Ws1 ; Wn1] (128 x 128) + b1
// bf16 MFMA 16x16x32. Block: 64 rows, 4 waves x 16 rows. W transposed +
// XOR-swizzled in LDS (bf16). A converted fp32->bf16 in flight.
// ---------------------------------------------------------------------------
__global__ __launch_bounds__(256) void gemm1_mfma(
    const float* __restrict__ x, const float* __restrict__ aggx,
    const float* __restrict__ Ws, const float* __restrict__ Wn,
    const float* __restrict__ b, float* __restrict__ h) {
  __shared__ __align__(16) unsigned short wt[128 * 128];  // [col][k], swizzled
  __shared__ float bs[HID];
  int tid = threadIdx.x;
  for (int i = tid; i < 128 * 128; i += 256) {
    int k = i >> 7, j = i & 127;
    float v = (k < 64) ? Ws[k * HID + j] : Wn[(k - 64) * HID + j];
    int idx = (j << 7) | k;
    wt[idx ^ ((j & 15) << 3)] = f2bf(v);
  }
  if (tid < HID) bs[tid] = b[tid];
  __syncthreads();

  int wave = tid >> 6, lane = tid & 63;
  int m = lane & 15, kg = lane >> 4;
  int rbase = blockIdx.x * 64 + wave * 16;
  int rowa = rbase + m;
  if (rowa >= N_NODES) rowa = N_NODES - 1;  // clamp (stores guarded)

  short8v a[4];
#pragma unroll
  for (int kt = 0; kt < 4; ++kt) {
    int c0 = kt * 32 + kg * 8;
    const float* src = (c0 < 64) ? (x + (size_t)rowa * 64 + c0)
                                 : (aggx + (size_t)rowa * 64 + (c0 - 64));
    float4 lo = *reinterpret_cast<const float4*>(src);
    float4 hi = *reinterpret_cast<const float4*>(src + 4);
    short8v av;
    av[0] = (short)f2bf(lo.x); av[1] = (short)f2bf(lo.y);
    av[2] = (short)f2bf(lo.z); av[3] = (short)f2bf(lo.w);
    av[4] = (short)f2bf(hi.x); av[5] = (short)f2bf(hi.y);
    av[6] = (short)f2bf(hi.z); av[7] = (short)f2bf(hi.w);
    a[kt] = av;
  }

  f32x4 acc[8];
#pragma unroll
  for (int nt = 0; nt < 8; ++nt) acc[nt] = (f32x4){0.f, 0.f, 0.f, 0.f};

#pragma unroll
  for (int nt = 0; nt < 8; ++nt) {
    int col = nt * 16 + m;
    int base = col << 7;
    int sw = (col & 15) << 3;
#pragma unroll
    for (int kt = 0; kt < 4; ++kt) {
      int idx = (base | (kt * 32 + kg * 8)) ^ sw;
      short8v bf = *reinterpret_cast<const short8v*>(&wt[idx]);
      acc[nt] = __builtin_amdgcn_mfma_f32_16x16x32_bf16(a[kt], bf, acc[nt], 0, 0, 0);
    }
  }

#pragma unroll
  for (int nt = 0; nt < 8; ++nt) {
    int col = nt * 16 + m;
    float bias = bs[col];
#pragma unroll
    for (int r = 0; r < 4; ++r) {
      int rr = rbase + kg * 4 + r;
      if (rr < N_NODES) h[(size_t)rr * HID + col] = acc[nt][r] + bias;
    }
  }
}

// ---------------------------------------------------------------------------
// bnstats: per-feature sum / sumsq over nodes
// ---------------------------------------------------------------------------
__global__ __launch_bounds__(256) void bnstats_kernel(
    const float* __restrict__ h, float* __restrict__ bnsum) {
  int f = threadIdx.x & 127;
  int half = threadIdx.x >> 7;
  int stride = gridDim.x * 2;
  float s = 0.f, q = 0.f;
  for (int r = blockIdx.x * 2 + half; r < N_NODES; r += stride) {
    float v = h[(size_t)r * HID + f];
    s += v;
    q += v * v;
  }
  __shared__ float ls[256];
  __shared__ float lq[256];
  ls[threadIdx.x] = s;
  lq[threadIdx.x] = q;
  __syncthreads();
  if (half == 0) {
    unsafeAtomicAdd(bnsum + f, ls[f] + ls[f + 128]);
    unsafeAtomicAdd(bnsum + 128 + f, lq[f] + lq[f + 128]);
  }
}

__global__ void bnfinal_kernel(const float* __restrict__ bnsum,
                               const float* __restrict__ gamma,
                               const float* __restrict__ beta,
                               float* __restrict__ scale,
                               float* __restrict__ shift) {
  int f = threadIdx.x;
  if (f >= HID) return;
  const float invn = 1.0f / (float)N_NODES;
  float mu = bnsum[f] * invn;
  float var = bnsum[128 + f] * invn - mu * mu;
  float sc = gamma[f] * rsqrtf(var + BN_EPS);
  scale[f] = sc;
  shift[f] = beta[f] - mu * sc;
}

// ---------------------------------------------------------------------------
// gemm2_mfma: hb = relu(bn(h)); [z | s] (N x 128) = hb (N x 128) @
// [Wn2 | Ws2] (128 x 128). z -> zbuf, s + b2 -> out. BN+ReLU fused in A-load.
// ---------------------------------------------------------------------------
__global__ __launch_bounds__(256) void gemm2_mfma(
    const float* __restrict__ h, const float* __restrict__ scale,
    const float* __restrict__ shift, const float* __restrict__ Wn,
    const float* __restrict__ Ws, const float* __restrict__ b,
    float* __restrict__ z, float* __restrict__ out) {
  __shared__ __align__(16) unsigned short wt[128 * 128];  // [col][k], swizzled
  __shared__ float scs[HID];
  __shared__ float shs[HID];
  __shared__ float bz[OUT_F];
  int tid = threadIdx.x;
  for (int i = tid; i < 128 * 128; i += 256) {
    int k = i >> 7, j = i & 127;
    float v = (j < 64) ? Wn[k * OUT_F + j] : Ws[k * OUT_F + (j - 64)];
    int idx = (j << 7) | k;
    wt[idx ^ ((j & 15) << 3)] = f2bf(v);
  }
  if (tid < HID) {
    scs[tid] = scale[tid];
    shs[tid] = shift[tid];
  }
  if (tid < OUT_F) bz[tid] = b[tid];
  __syncthreads();

  int wave = tid >> 6, lane = tid & 63;
  int m = lane & 15, kg = lane >> 4;
  int rbase = blockIdx.x * 64 + wave * 16;
  int rowa = rbase + m;
  if (rowa >= N_NODES) rowa = N_NODES - 1;

  short8v a[4];
#pragma unroll
  for (int kt = 0; kt < 4; ++kt) {
    int c0 = kt * 32 + kg * 8;
    const float* src = h + (size_t)rowa * HID + c0;
    float4 lo = *reinterpret_cast<const float4*>(src);
    float4 hi = *reinterpret_cast<const float4*>(src + 4);
    float4 sc0 = *reinterpret_cast<const float4*>(&scs[c0]);
    float4 sc1 = *reinterpret_cast<const float4*>(&scs[c0 + 4]);
    float4 sh0 = *reinterpret_cast<const float4*>(&shs[c0]);
    float4 sh1 = *reinterpret_cast<const float4*>(&shs[c0 + 4]);
    short8v av;
    av[0] = (short)f2bf(fmaxf(lo.x * sc0.x + sh0.x, 0.f));
    av[1] = (short)f2bf(fmaxf(lo.y * sc0.y + sh0.y, 0.f));
    av[2] = (short)f2bf(fmaxf(lo.z * sc0.z + sh0.z, 0.f));
    av[3] = (short)f2bf(fmaxf(lo.w * sc0.w + sh0.w, 0.f));
    av[4] = (short)f2bf(fmaxf(hi.x * sc1.x + sh1.x, 0.f));
    av[5] = (short)f2bf(fmaxf(hi.y * sc1.y + sh1.y, 0.f));
    av[6] = (short)f2bf(fmaxf(hi.z * sc1.z + sh1.z, 0.f));
    av[7] = (short)f2bf(fmaxf(hi.w * sc1.w + sh1.w, 0.f));
    a[kt] = av;
  }

  f32x4 acc[8];
#pragma unroll
  for (int nt = 0; nt < 8; ++nt) acc[nt] = (f32x4){0.f, 0.f, 0.f, 0.f};

#pragma unroll
  for (int nt = 0; nt < 8; ++nt) {
    int col = nt * 16 + m;
    int base = col << 7;
    int sw = (col & 15) << 3;
#pragma unroll
    for (int kt = 0; kt < 4; ++kt) {
      int idx = (base | (kt * 32 + kg * 8)) ^ sw;
      short8v bf = *reinterpret_cast<const short8v*>(&wt[idx]);
      acc[nt] = __builtin_amdgcn_mfma_f32_16x16x32_bf16(a[kt], bf, acc[nt], 0, 0, 0);
    }
  }

#pragma unroll
  for (int nt = 0; nt < 8; ++nt) {
    int col = nt * 16 + m;
#pragma unroll
    for (int r = 0; r < 4; ++r) {
      int rr = rbase + kg * 4 + r;
      if (rr < N_NODES) {
        float v = acc[nt][r];
        if (col < 64)
          z[(size_t)rr * OUT_F + col] = v;
        else
          out[(size_t)rr * OUT_F + (col - 64)] = v + bz[col - 64];
      }
    }
  }
}

// ---------------------------------------------------------------------------
extern "C" void kernel_launch(void* const* d_in, const int* in_sizes, int n_in,
                              void* d_out, int out_size, void* d_ws,
                              size_t ws_size, hipStream_t stream) {
  const float* x = (const float*)d_in[0];
  const int* esrc = (const int*)d_in[1];
  const int* edst = (const int*)d_in[2];
  const float* Ws1 = (const float*)d_in[3];
  const float* Wn1 = (const float*)d_in[4];
  const float* b1 = (const float*)d_in[5];
  const float* gamma = (const float*)d_in[6];
  const float* beta = (const float*)d_in[7];
  const float* Ws2 = (const float*)d_in[8];
  const float* Wn2 = (const float*)d_in[9];
  const float* b2 = (const float*)d_in[10];
  float* out = (float*)d_out;

  float* ws = (float*)d_ws;
  float* bnsum = ws;                        // 256
  float* bnscale = ws + 256;                // 128
  float* bnshift = ws + 384;                // 128
  int* cursor = (int*)(ws + 512);           // N (degrees after pass1)
  int* rowstart = cursor + N_NODES;         // N+1
  int* bsum = rowstart + N_NODES + 1;       // SCAN_NBLK
  int* boff = bsum + SCAN_NBLK;             // SCAN_NBLK
  unsigned short* pos16 =
      (unsigned short*)(boff + SCAN_NBLK);  // E ushort = E/2 ints
  int* csr = (int*)(pos16 + N_EDGES);       // E
  float* aggz = (float*)(csr + N_EDGES);    // N*64 (aggx for L1, then z for L2)
  float* h = aggz + (size_t)N_NODES * 64;   // N*128

  // zero bnsum/scale/shift + cursor
  hipMemsetAsync(d_ws, 0, (512 + (size_t)N_NODES) * sizeof(float), stream);

  const int e4grid = (N_EDGES / 4 + 255) / 256;
  pass1_kernel<<<e4grid, 256, 0, stream>>>(edst, cursor, pos16);
  blocksum_kernel<<<SCAN_NBLK, 256, 0, stream>>>(cursor, bsum);
  scanb_kernel<<<1, 512, 0, stream>>>(bsum, boff, rowstart);
  writerow_kernel<<<SCAN_NBLK, 256, 0, stream>>>(cursor, boff, rowstart);
  scatter_kernel<<<e4grid, 256, 0, stream>>>(esrc, edst, pos16, rowstart, csr);

  const int ggrid = (N_NODES + 63) / 64;
  // layer 1: aggx = mean_in(x); h = [x|aggx] @ [Ws1;Wn1] + b1
  agg_kernel<false><<<(N_NODES + 15) / 16, 256, 0, stream>>>(x, rowstart, csr,
                                                             aggz);
  gemm1_mfma<<<ggrid, 256, 0, stream>>>(x, aggz, Ws1, Wn1, b1, h);

  // batchnorm stats
  bnstats_kernel<<<1024, 256, 0, stream>>>(h, bnsum);
  bnfinal_kernel<<<1, 128, 0, stream>>>(bnsum, gamma, beta, bnscale, bnshift);

  // layer 2: [z|s] = relu(bn(h)) @ [Wn2|Ws2]; out = s + b2; out += mean_in(z)
  gemm2_mfma<<<ggrid, 256, 0, stream>>>(h, bnscale, bnshift, Wn2, Ws2, b2,
                                        aggz, out);
  agg_kernel<true><<<(N_NODES + 15) / 16, 256, 0, stream>>>(aggz, rowstart, csr,
                                                            out);
}

// Round 9
// 222.063 us; speedup vs baseline: 10.4865x; 1.1074x over previous
//
#include <hip/hip_runtime.h>

#define N_NODES 100000
#define N_EDGES 800000
#define IN_F 64
#define HID 128
#define OUT_F 64
#define BN_EPS 1e-5f
#define SCAN_NBLK ((N_NODES + 255) / 256)  // 391

typedef __attribute__((ext_vector_type(8))) short short8v;
typedef __attribute__((ext_vector_type(4))) float f32x4;

// fp32 -> bf16 round-to-nearest-even
static __device__ __forceinline__ unsigned short f2bf(float f) {
  unsigned u = __float_as_uint(f);
  return (unsigned short)((u + 0x7FFFu + ((u >> 16) & 1u)) >> 16);
}
static __device__ __forceinline__ float bflo(unsigned u) {
  return __uint_as_float(u << 16);
}
static __device__ __forceinline__ float bfhi(unsigned u) {
  return __uint_as_float(u & 0xFFFF0000u);
}

// ---------------------------------------------------------------------------
// cvt: xb = bf16(x)   (8 elems/thread: 2 float4 in, 1 uint4 out)
// ---------------------------------------------------------------------------
__global__ __launch_bounds__(256) void cvt_kernel(
    const float* __restrict__ x, unsigned short* __restrict__ xb) {
  int t = blockIdx.x * 256 + threadIdx.x;
  if (t >= N_NODES * IN_F / 8) return;
  float4 a = reinterpret_cast<const float4*>(x)[t * 2];
  float4 b = reinterpret_cast<const float4*>(x)[t * 2 + 1];
  uint4 o;
  o.x = (unsigned)f2bf(a.x) | ((unsigned)f2bf(a.y) << 16);
  o.y = (unsigned)f2bf(a.z) | ((unsigned)f2bf(a.w) << 16);
  o.z = (unsigned)f2bf(b.x) | ((unsigned)f2bf(b.y) << 16);
  o.w = (unsigned)f2bf(b.z) | ((unsigned)f2bf(b.w) << 16);
  reinterpret_cast<uint4*>(xb)[t] = o;
}

// ---------------------------------------------------------------------------
// pass1: pos16[e] = cursor[dst]++  (atomic pass gives rank AND histogram)
// ---------------------------------------------------------------------------
__global__ __launch_bounds__(256) void pass1_kernel(
    const int* __restrict__ edst, int* __restrict__ cursor,
    unsigned short* __restrict__ pos16) {
  int t = blockIdx.x * 256 + threadIdx.x;
  if (t >= N_EDGES / 4) return;
  int4 d = reinterpret_cast<const int4*>(edst)[t];
  ushort4 p;
  p.x = (unsigned short)atomicAdd(cursor + d.x, 1);
  p.y = (unsigned short)atomicAdd(cursor + d.y, 1);
  p.z = (unsigned short)atomicAdd(cursor + d.z, 1);
  p.w = (unsigned short)atomicAdd(cursor + d.w, 1);
  reinterpret_cast<ushort4*>(pos16)[t] = p;
}

// ---------------------------------------------------------------------------
// hierarchical scan over cursor (= degrees): blocksum -> scanb -> writerow
// ---------------------------------------------------------------------------
__global__ __launch_bounds__(256) void blocksum_kernel(
    const int* __restrict__ degi, int* __restrict__ bsum) {
  __shared__ int ls[256];
  int i = blockIdx.x * 256 + threadIdx.x;
  ls[threadIdx.x] = (i < N_NODES) ? degi[i] : 0;
  __syncthreads();
  for (int off = 128; off > 0; off >>= 1) {
    if (threadIdx.x < off) ls[threadIdx.x] += ls[threadIdx.x + off];
    __syncthreads();
  }
  if (threadIdx.x == 0) bsum[blockIdx.x] = ls[0];
}

__global__ __launch_bounds__(512) void scanb_kernel(
    const int* __restrict__ bsum, int* __restrict__ boff,
    int* __restrict__ rowstart) {
  __shared__ int ls[512];
  int t = threadIdx.x;
  int v = (t < SCAN_NBLK) ? bsum[t] : 0;
  ls[t] = v;
  __syncthreads();
  for (int off = 1; off < 512; off <<= 1) {
    int u = (t >= off) ? ls[t - off] : 0;
    __syncthreads();
    ls[t] += u;
    __syncthreads();
  }
  if (t < SCAN_NBLK) boff[t] = ls[t] - v;  // exclusive
  if (t == 511) rowstart[N_NODES] = ls[511];
}

__global__ __launch_bounds__(256) void writerow_kernel(
    const int* __restrict__ degi, const int* __restrict__ boff,
    int* __restrict__ rowstart) {
  __shared__ int ls[256];
  int i = blockIdx.x * 256 + threadIdx.x;
  int t = threadIdx.x;
  int v = (i < N_NODES) ? degi[i] : 0;
  ls[t] = v;
  __syncthreads();
  for (int off = 1; off < 256; off <<= 1) {
    int u = (t >= off) ? ls[t - off] : 0;
    __syncthreads();
    ls[t] += u;
    __syncthreads();
  }
  if (i < N_NODES) rowstart[i] = boff[blockIdx.x] + ls[t] - v;
}

// ---------------------------------------------------------------------------
// scatter: csr[rowstart[dst] + pos16[e]] = src   (pure stores, no atomics)
// ---------------------------------------------------------------------------
__global__ __launch_bounds__(256) void scatter_kernel(
    const int* __restrict__ esrc, const int* __restrict__ edst,
    const unsigned short* __restrict__ pos16,
    const int* __restrict__ rowstart, int* __restrict__ csr) {
  int t = blockIdx.x * 256 + threadIdx.x;
  if (t >= N_EDGES / 4) return;
  int4 s = reinterpret_cast<const int4*>(esrc)[t];
  int4 d = reinterpret_cast<const int4*>(edst)[t];
  ushort4 p = reinterpret_cast<const ushort4*>(pos16)[t];
  csr[rowstart[d.x] + p.x] = s.x;
  csr[rowstart[d.y] + p.y] = s.y;
  csr[rowstart[d.z] + p.z] = s.z;
  csr[rowstart[d.w] + p.w] = s.w;
}

// ---------------------------------------------------------------------------
// aggb: mean over in-edges of bf16 feat rows [N][64].
// 8 lanes/node, 16B (8 bf16) per lane; fp32 accumulate.
// ACC=false: write bf16 to dstb.  ACC=true: dstf += mean (fp32).
// ---------------------------------------------------------------------------
template <bool ACC>
__global__ __launch_bounds__(256) void aggb_kernel(
    const unsigned short* __restrict__ featb, const int* __restrict__ rowstart,
    const int* __restrict__ csr, unsigned short* __restrict__ dstb,
    float* __restrict__ dstf) {
  int n = blockIdx.x * 32 + (threadIdx.x >> 3);
  int j = threadIdx.x & 7;
  if (n >= N_NODES) return;
  int r0 = rowstart[n];
  int r1 = rowstart[n + 1];
  float acc[8] = {0.f, 0.f, 0.f, 0.f, 0.f, 0.f, 0.f, 0.f};
  int i = r0;
  for (; i + 1 < r1; i += 2) {
    int s0 = csr[i];
    int s1 = csr[i + 1];
    uint4 v0 = *reinterpret_cast<const uint4*>(featb + (size_t)s0 * 64 + j * 8);
    uint4 v1 = *reinterpret_cast<const uint4*>(featb + (size_t)s1 * 64 + j * 8);
    acc[0] += bflo(v0.x) + bflo(v1.x);
    acc[1] += bfhi(v0.x) + bfhi(v1.x);
    acc[2] += bflo(v0.y) + bflo(v1.y);
    acc[3] += bfhi(v0.y) + bfhi(v1.y);
    acc[4] += bflo(v0.z) + bflo(v1.z);
    acc[5] += bfhi(v0.z) + bfhi(v1.z);
    acc[6] += bflo(v0.w) + bflo(v1.w);
    acc[7] += bfhi(v0.w) + bfhi(v1.w);
  }
  if (i < r1) {
    int s0 = csr[i];
    uint4 v0 = *reinterpret_cast<const uint4*>(featb + (size_t)s0 * 64 + j * 8);
    acc[0] += bflo(v0.x);
    acc[1] += bfhi(v0.x);
    acc[2] += bflo(v0.y);
    acc[3] += bfhi(v0.y);
    acc[4] += bflo(v0.z);
    acc[5] += bfhi(v0.z);
    acc[6] += bflo(v0.w);
    acc[7] += bfhi(v0.w);
  }
  int deg = r1 - r0;
  float rd = 1.0f / (float)(deg > 0 ? deg : 1);
  if (ACC) {
    float4* dp = reinterpret_cast<float4*>(dstf + (size_t)n * 64 + j * 8);
    float4 p0 = dp[0], p1 = dp[1];
    p0.x += acc[0] * rd; p0.y += acc[1] * rd;
    p0.z += acc[2] * rd; p0.w += acc[3] * rd;
    p1.x += acc[4] * rd; p1.y += acc[5] * rd;
    p1.z += acc[6] * rd; p1.w += acc[7] * rd;
    dp[0] = p0; dp[1] = p1;
  } else {
    uint4 o;
    o.x = (unsigned)f2bf(acc[0] * rd) | ((unsigned)f2bf(acc[1] * rd) << 16);
    o.y = (unsigned)f2bf(acc[2] * rd) | ((unsigned)f2bf(acc[3] * rd) << 16);
    o.z = (unsigned)f2bf(acc[4] * rd) | ((unsigned)f2bf(acc[5] * rd) << 16);
    o.w = (unsigned)f2bf(acc[6] * rd) | ((unsigned)f2bf(acc[7] * rd) << 16);
    *reinterpret_cast<uint4*>(dstb + (size_t)n * 64 + j * 8) = o;
  }
}

// ---------------------------------------------------------------------------
// gemm1_mfma: hb[N x 128] (bf16) = [xb | aggxb] @ [Ws1 ; Wn1] + b1
// A rows already bf16 -> A-load is one 16B load. W transposed + XOR-swizzled
// in LDS. C/D: col = lane&15, row = (lane>>4)*4 + reg.
// ---------------------------------------------------------------------------
__global__ __launch_bounds__(256) void gemm1_mfma(
    const unsigned short* __restrict__ xb,
    const unsigned short* __restrict__ aggxb, const float* __restrict__ Ws,
    const float* __restrict__ Wn, const float* __restrict__ b,
    unsigned short* __restrict__ hb) {
  __shared__ __align__(16) unsigned short wt[128 * 128];  // [col][k], swizzled
  __shared__ float bs[HID];
  int tid = threadIdx.x;
  for (int i = tid; i < 128 * 128; i += 256) {
    int k = i >> 7, j = i & 127;
    float v = (k < 64) ? Ws[k * HID + j] : Wn[(k - 64) * HID + j];
    int idx = (j << 7) | k;
    wt[idx ^ ((j & 15) << 3)] = f2bf(v);
  }
  if (tid < HID) bs[tid] = b[tid];
  __syncthreads();

  int wave = tid >> 6, lane = tid & 63;
  int m = lane & 15, kg = lane >> 4;
  int rbase = blockIdx.x * 64 + wave * 16;
  int rowa = rbase + m;
  if (rowa >= N_NODES) rowa = N_NODES - 1;  // clamp (stores guarded)

  short8v a[4];
#pragma unroll
  for (int kt = 0; kt < 4; ++kt) {
    int c0 = kt * 32 + kg * 8;
    const unsigned short* src = (c0 < 64)
                                    ? (xb + (size_t)rowa * 64 + c0)
                                    : (aggxb + (size_t)rowa * 64 + (c0 - 64));
    a[kt] = *reinterpret_cast<const short8v*>(src);
  }

  f32x4 acc[8];
#pragma unroll
  for (int nt = 0; nt < 8; ++nt) acc[nt] = (f32x4){0.f, 0.f, 0.f, 0.f};

#pragma unroll
  for (int nt = 0; nt < 8; ++nt) {
    int col = nt * 16 + m;
    int base = col << 7;
    int sw = (col & 15) << 3;
#pragma unroll
    for (int kt = 0; kt < 4; ++kt) {
      int idx = (base | (kt * 32 + kg * 8)) ^ sw;
      short8v bf = *reinterpret_cast<const short8v*>(&wt[idx]);
      acc[nt] = __builtin_amdgcn_mfma_f32_16x16x32_bf16(a[kt], bf, acc[nt], 0, 0, 0);
    }
  }

#pragma unroll
  for (int nt = 0; nt < 8; ++nt) {
    int col = nt * 16 + m;
    float bias = bs[col];
#pragma unroll
    for (int r = 0; r < 4; ++r) {
      int rr = rbase + kg * 4 + r;
      if (rr < N_NODES) hb[(size_t)rr * HID + col] = f2bf(acc[nt][r] + bias);
    }
  }
}

// ---------------------------------------------------------------------------
// bnstats: per-feature sum / sumsq over nodes (bf16 h)
// ---------------------------------------------------------------------------
__global__ __launch_bounds__(256) void bnstats_kernel(
    const unsigned short* __restrict__ hb, float* __restrict__ bnsum) {
  int f = threadIdx.x & 127;
  int half = threadIdx.x >> 7;
  int stride = gridDim.x * 2;
  float s = 0.f, q = 0.f;
  for (int r = blockIdx.x * 2 + half; r < N_NODES; r += stride) {
    float v = __uint_as_float((unsigned)hb[(size_t)r * HID + f] << 16);
    s += v;
    q += v * v;
  }
  __shared__ float ls[256];
  __shared__ float lq[256];
  ls[threadIdx.x] = s;
  lq[threadIdx.x] = q;
  __syncthreads();
  if (half == 0) {
    unsafeAtomicAdd(bnsum + f, ls[f] + ls[f + 128]);
    unsafeAtomicAdd(bnsum + 128 + f, lq[f] + lq[f + 128]);
  }
}

__global__ void bnfinal_kernel(const float* __restrict__ bnsum,
                               const float* __restrict__ gamma,
                               const float* __restrict__ beta,
                               float* __restrict__ scale,
                               float* __restrict__ shift) {
  int f = threadIdx.x;
  if (f >= HID) return;
  const float invn = 1.0f / (float)N_NODES;
  float mu = bnsum[f] * invn;
  float var = bnsum[128 + f] * invn - mu * mu;
  float sc = gamma[f] * rsqrtf(var + BN_EPS);
  scale[f] = sc;
  shift[f] = beta[f] - mu * sc;
}

// ---------------------------------------------------------------------------
// gemm2_mfma: hbn = relu(bn(hb)); [z | s] = hbn @ [Wn2 | Ws2].
// z -> zb (bf16), s + b2 -> out (fp32). BN+ReLU fused in A-load.
// ---------------------------------------------------------------------------
__global__ __launch_bounds__(256) void gemm2_mfma(
    const unsigned short* __restrict__ hb, const float* __restrict__ scale,
    const float* __restrict__ shift, const float* __restrict__ Wn,
    const float* __restrict__ Ws, const float* __restrict__ b,
    unsigned short* __restrict__ zb, float* __restrict__ out) {
  __shared__ __align__(16) unsigned short wt[128 * 128];  // [col][k], swizzled
  __shared__ float scs[HID];
  __shared__ float shs[HID];
  __shared__ float bz[OUT_F];
  int tid = threadIdx.x;
  for (int i = tid; i < 128 * 128; i += 256) {
    int k = i >> 7, j = i & 127;
    float v = (j < 64) ? Wn[k * OUT_F + j] : Ws[k * OUT_F + (j - 64)];
    int idx = (j << 7) | k;
    wt[idx ^ ((j & 15) << 3)] = f2bf(v);
  }
  if (tid < HID) {
    scs[tid] = scale[tid];
    shs[tid] = shift[tid];
  }
  if (tid < OUT_F) bz[tid] = b[tid];
  __syncthreads();

  int wave = tid >> 6, lane = tid & 63;
  int m = lane & 15, kg = lane >> 4;
  int rbase = blockIdx.x * 64 + wave * 16;
  int rowa = rbase + m;
  if (rowa >= N_NODES) rowa = N_NODES - 1;

  short8v a[4];
#pragma unroll
  for (int kt = 0; kt < 4; ++kt) {
    int c0 = kt * 32 + kg * 8;
    uint4 raw = *reinterpret_cast<const uint4*>(hb + (size_t)rowa * HID + c0);
    float4 sc0 = *reinterpret_cast<const float4*>(&scs[c0]);
    float4 sc1 = *reinterpret_cast<const float4*>(&scs[c0 + 4]);
    float4 sh0 = *reinterpret_cast<const float4*>(&shs[c0]);
    float4 sh1 = *reinterpret_cast<const float4*>(&shs[c0 + 4]);
    short8v av;
    av[0] = (short)f2bf(fmaxf(bflo(raw.x) * sc0.x + sh0.x, 0.f));
    av[1] = (short)f2bf(fmaxf(bfhi(raw.x) * sc0.y + sh0.y, 0.f));
    av[2] = (short)f2bf(fmaxf(bflo(raw.y) * sc0.z + sh0.z, 0.f));
    av[3] = (short)f2bf(fmaxf(bfhi(raw.y) * sc0.w + sh0.w, 0.f));
    av[4] = (short)f2bf(fmaxf(bflo(raw.z) * sc1.x + sh1.x, 0.f));
    av[5] = (short)f2bf(fmaxf(bfhi(raw.z) * sc1.y + sh1.y, 0.f));
    av[6] = (short)f2bf(fmaxf(bflo(raw.w) * sc1.z + sh1.z, 0.f));
    av[7] = (short)f2bf(fmaxf(bfhi(raw.w) * sc1.w + sh1.w, 0.f));
    a[kt] = av;
  }

  f32x4 acc[8];
#pragma unroll
  for (int nt = 0; nt < 8; ++nt) acc[nt] = (f32x4){0.f, 0.f, 0.f, 0.f};

#pragma unroll
  for (int nt = 0; nt < 8; ++nt) {
    int col = nt * 16 + m;
    int base = col << 7;
    int sw = (col & 15) << 3;
#pragma unroll
    for (int kt = 0; kt < 4; ++kt) {
      int idx = (base | (kt * 32 + kg * 8)) ^ sw;
      short8v bf = *reinterpret_cast<const short8v*>(&wt[idx]);
      acc[nt] = __builtin_amdgcn_mfma_f32_16x16x32_bf16(a[kt], bf, acc[nt], 0, 0, 0);
    }
  }

#pragma unroll
  for (int nt = 0; nt < 8; ++nt) {
    int col = nt * 16 + m;
#pragma unroll
    for (int r = 0; r < 4; ++r) {
      int rr = rbase + kg * 4 + r;
      if (rr < N_NODES) {
        float v = acc[nt][r];
        if (col < 64)
          zb[(size_t)rr * OUT_F + col] = f2bf(v);
        else
          out[(size_t)rr * OUT_F + (col - 64)] = v + bz[col - 64];
      }
    }
  }
}

// ---------------------------------------------------------------------------
extern "C" void kernel_launch(void* const* d_in, const int* in_sizes, int n_in,
                              void* d_out, int out_size, void* d_ws,
                              size_t ws_size, hipStream_t stream) {
  const float* x = (const float*)d_in[0];
  const int* esrc = (const int*)d_in[1];
  const int* edst = (const int*)d_in[2];
  const float* Ws1 = (const float*)d_in[3];
  const float* Wn1 = (const float*)d_in[4];
  const float* b1 = (const float*)d_in[5];
  const float* gamma = (const float*)d_in[6];
  const float* beta = (const float*)d_in[7];
  const float* Ws2 = (const float*)d_in[8];
  const float* Wn2 = (const float*)d_in[9];
  const float* b2 = (const float*)d_in[10];
  float* out = (float*)d_out;

  float* ws = (float*)d_ws;
  float* bnsum = ws;                         // 256
  float* bnscale = ws + 256;                 // 128
  float* bnshift = ws + 384;                 // 128
  int* cursor = (int*)(ws + 512);            // N (degrees after pass1)
  int* rowstart = cursor + N_NODES;          // N+1
  int* bsum = rowstart + N_NODES + 1;        // SCAN_NBLK
  int* boff = bsum + SCAN_NBLK;              // SCAN_NBLK
  int* csr = boff + SCAN_NBLK;               // E  (4B aligned)
  int pos16_off = ((512 + 2 * N_NODES + 1 + 2 * SCAN_NBLK + N_EDGES) + 3) & ~3;
  unsigned short* pos16 = (unsigned short*)(ws + pos16_off);       // E ushort
  unsigned short* xb = (unsigned short*)(ws + pos16_off + N_EDGES / 2);
  unsigned short* aggxb = xb + (size_t)N_NODES * 64;               // also zb
  unsigned short* hb = aggxb + (size_t)N_NODES * 64;               // N*128

  // zero bnsum/scale/shift + cursor
  hipMemsetAsync(d_ws, 0, (512 + (size_t)N_NODES) * sizeof(float), stream);

  const int e4grid = (N_EDGES / 4 + 255) / 256;
  cvt_kernel<<<(N_NODES * IN_F / 8 + 255) / 256, 256, 0, stream>>>(x, xb);
  pass1_kernel<<<e4grid, 256, 0, stream>>>(edst, cursor, pos16);
  blocksum_kernel<<<SCAN_NBLK, 256, 0, stream>>>(cursor, bsum);
  scanb_kernel<<<1, 512, 0, stream>>>(bsum, boff, rowstart);
  writerow_kernel<<<SCAN_NBLK, 256, 0, stream>>>(cursor, boff, rowstart);
  scatter_kernel<<<e4grid, 256, 0, stream>>>(esrc, edst, pos16, rowstart, csr);

  const int ggrid = (N_NODES + 63) / 64;
  const int agrid = (N_NODES + 31) / 32;
  // layer 1: aggxb = mean_in(xb); hb = [xb|aggxb] @ [Ws1;Wn1] + b1
  aggb_kernel<false><<<agrid, 256, 0, stream>>>(xb, rowstart, csr, aggxb,
                                                nullptr);
  gemm1_mfma<<<ggrid, 256, 0, stream>>>(xb, aggxb, Ws1, Wn1, b1, hb);

  // batchnorm stats
  bnstats_kernel<<<1024, 256, 0, stream>>>(hb, bnsum);
  bnfinal_kernel<<<1, 128, 0, stream>>>(bnsum, gamma, beta, bnscale, bnshift);

  // layer 2: [zb|s] = relu(bn(hb)) @ [Wn2|Ws2]; out = s + b2; out += mean(zb)
  gemm2_mfma<<<ggrid, 256, 0, stream>>>(hb, bnscale, bnshift, Wn2, Ws2, b2,
                                        aggxb, out);
  aggb_kernel<true><<<agrid, 256, 0, stream>>>(aggxb, rowstart, csr, nullptr,
                                               out);
}

// Round 10
// 221.895 us; speedup vs baseline: 10.4944x; 1.0008x over previous
//
#include <hip/hip_runtime.h>

#define N_NODES 100000
#define N_EDGES 800000
#define IN_F 64
#define HID 128
#define OUT_F 64
#define BN_EPS 1e-5f
#define SCAN_NBLK ((N_NODES + 255) / 256)  // 391

typedef __attribute__((ext_vector_type(8))) short short8v;
typedef __attribute__((ext_vector_type(4))) float f32x4;

// fp32 -> bf16 round-to-nearest-even
static __device__ __forceinline__ unsigned short f2bf(float f) {
  unsigned u = __float_as_uint(f);
  return (unsigned short)((u + 0x7FFFu + ((u >> 16) & 1u)) >> 16);
}
static __device__ __forceinline__ float bflo(unsigned u) {
  return __uint_as_float(u << 16);
}
static __device__ __forceinline__ float bfhi(unsigned u) {
  return __uint_as_float(u & 0xFFFF0000u);
}

// ---------------------------------------------------------------------------
// zero: cursor[0..N) = 0  (int4 stores; replaces 40us rocclr fillBuffer)
// ---------------------------------------------------------------------------
__global__ __launch_bounds__(256) void zero_kernel(int* __restrict__ cursor) {
  int t = blockIdx.x * 256 + threadIdx.x;
  int4 z = {0, 0, 0, 0};
  if (t * 4 + 3 < N_NODES) {
    reinterpret_cast<int4*>(cursor)[t] = z;
  } else if (t * 4 < N_NODES) {
    for (int i = t * 4; i < N_NODES; ++i) cursor[i] = 0;
  }
}

// ---------------------------------------------------------------------------
// cvt: xb = bf16(x)   (8 elems/thread: 2 float4 in, 1 uint4 out)
// ---------------------------------------------------------------------------
__global__ __launch_bounds__(256) void cvt_kernel(
    const float* __restrict__ x, unsigned short* __restrict__ xb) {
  int t = blockIdx.x * 256 + threadIdx.x;
  if (t >= N_NODES * IN_F / 8) return;
  float4 a = reinterpret_cast<const float4*>(x)[t * 2];
  float4 b = reinterpret_cast<const float4*>(x)[t * 2 + 1];
  uint4 o;
  o.x = (unsigned)f2bf(a.x) | ((unsigned)f2bf(a.y) << 16);
  o.y = (unsigned)f2bf(a.z) | ((unsigned)f2bf(a.w) << 16);
  o.z = (unsigned)f2bf(b.x) | ((unsigned)f2bf(b.y) << 16);
  o.w = (unsigned)f2bf(b.z) | ((unsigned)f2bf(b.w) << 16);
  reinterpret_cast<uint4*>(xb)[t] = o;
}

// ---------------------------------------------------------------------------
// pass1: pos16[e] = cursor[dst]++  (atomic pass gives rank AND histogram)
// ---------------------------------------------------------------------------
__global__ __launch_bounds__(256) void pass1_kernel(
    const int* __restrict__ edst, int* __restrict__ cursor,
    unsigned short* __restrict__ pos16) {
  int t = blockIdx.x * 256 + threadIdx.x;
  if (t >= N_EDGES / 4) return;
  int4 d = reinterpret_cast<const int4*>(edst)[t];
  ushort4 p;
  p.x = (unsigned short)atomicAdd(cursor + d.x, 1);
  p.y = (unsigned short)atomicAdd(cursor + d.y, 1);
  p.z = (unsigned short)atomicAdd(cursor + d.z, 1);
  p.w = (unsigned short)atomicAdd(cursor + d.w, 1);
  reinterpret_cast<ushort4*>(pos16)[t] = p;
}

// ---------------------------------------------------------------------------
// hierarchical scan over cursor (= degrees): blocksum -> scanb -> writerow
// ---------------------------------------------------------------------------
__global__ __launch_bounds__(256) void blocksum_kernel(
    const int* __restrict__ degi, int* __restrict__ bsum) {
  __shared__ int ls[256];
  int i = blockIdx.x * 256 + threadIdx.x;
  ls[threadIdx.x] = (i < N_NODES) ? degi[i] : 0;
  __syncthreads();
  for (int off = 128; off > 0; off >>= 1) {
    if (threadIdx.x < off) ls[threadIdx.x] += ls[threadIdx.x + off];
    __syncthreads();
  }
  if (threadIdx.x == 0) bsum[blockIdx.x] = ls[0];
}

// also zeroes bnsum (used much later by bnstats) to avoid a memset dispatch
__global__ __launch_bounds__(512) void scanb_kernel(
    const int* __restrict__ bsum, int* __restrict__ boff,
    int* __restrict__ rowstart, float* __restrict__ bnsum) {
  __shared__ int ls[512];
  int t = threadIdx.x;
  if (t < 256) bnsum[t] = 0.f;
  int v = (t < SCAN_NBLK) ? bsum[t] : 0;
  ls[t] = v;
  __syncthreads();
  for (int off = 1; off < 512; off <<= 1) {
    int u = (t >= off) ? ls[t - off] : 0;
    __syncthreads();
    ls[t] += u;
    __syncthreads();
  }
  if (t < SCAN_NBLK) boff[t] = ls[t] - v;  // exclusive
  if (t == 511) rowstart[N_NODES] = ls[511];
}

__global__ __launch_bounds__(256) void writerow_kernel(
    const int* __restrict__ degi, const int* __restrict__ boff,
    int* __restrict__ rowstart) {
  __shared__ int ls[256];
  int i = blockIdx.x * 256 + threadIdx.x;
  int t = threadIdx.x;
  int v = (i < N_NODES) ? degi[i] : 0;
  ls[t] = v;
  __syncthreads();
  for (int off = 1; off < 256; off <<= 1) {
    int u = (t >= off) ? ls[t - off] : 0;
    __syncthreads();
    ls[t] += u;
    __syncthreads();
  }
  if (i < N_NODES) rowstart[i] = boff[blockIdx.x] + ls[t] - v;
}

// ---------------------------------------------------------------------------
// scatter: csr[rowstart[dst] + pos16[e]] = src   (pure stores, no atomics)
// ---------------------------------------------------------------------------
__global__ __launch_bounds__(256) void scatter_kernel(
    const int* __restrict__ esrc, const int* __restrict__ edst,
    const unsigned short* __restrict__ pos16,
    const int* __restrict__ rowstart, int* __restrict__ csr) {
  int t = blockIdx.x * 256 + threadIdx.x;
  if (t >= N_EDGES / 4) return;
  int4 s = reinterpret_cast<const int4*>(esrc)[t];
  int4 d = reinterpret_cast<const int4*>(edst)[t];
  ushort4 p = reinterpret_cast<const ushort4*>(pos16)[t];
  csr[rowstart[d.x] + p.x] = s.x;
  csr[rowstart[d.y] + p.y] = s.y;
  csr[rowstart[d.z] + p.z] = s.z;
  csr[rowstart[d.w] + p.w] = s.w;
}

// ---------------------------------------------------------------------------
// aggb: mean over in-edges of bf16 feat rows [N][64].
// 8 lanes/node, 16B (8 bf16) per lane; fp32 accumulate.
// ACC=false: write bf16 to dstb.  ACC=true: dstf += mean (fp32).
// ---------------------------------------------------------------------------
template <bool ACC>
__global__ __launch_bounds__(256) void aggb_kernel(
    const unsigned short* __restrict__ featb, const int* __restrict__ rowstart,
    const int* __restrict__ csr, unsigned short* __restrict__ dstb,
    float* __restrict__ dstf) {
  int n = blockIdx.x * 32 + (threadIdx.x >> 3);
  int j = threadIdx.x & 7;
  if (n >= N_NODES) return;
  int r0 = rowstart[n];
  int r1 = rowstart[n + 1];
  float acc[8] = {0.f, 0.f, 0.f, 0.f, 0.f, 0.f, 0.f, 0.f};
  int i = r0;
  for (; i + 1 < r1; i += 2) {
    int s0 = csr[i];
    int s1 = csr[i + 1];
    uint4 v0 = *reinterpret_cast<const uint4*>(featb + (size_t)s0 * 64 + j * 8);
    uint4 v1 = *reinterpret_cast<const uint4*>(featb + (size_t)s1 * 64 + j * 8);
    acc[0] += bflo(v0.x) + bflo(v1.x);
    acc[1] += bfhi(v0.x) + bfhi(v1.x);
    acc[2] += bflo(v0.y) + bflo(v1.y);
    acc[3] += bfhi(v0.y) + bfhi(v1.y);
    acc[4] += bflo(v0.z) + bflo(v1.z);
    acc[5] += bfhi(v0.z) + bfhi(v1.z);
    acc[6] += bflo(v0.w) + bflo(v1.w);
    acc[7] += bfhi(v0.w) + bfhi(v1.w);
  }
  if (i < r1) {
    int s0 = csr[i];
    uint4 v0 = *reinterpret_cast<const uint4*>(featb + (size_t)s0 * 64 + j * 8);
    acc[0] += bflo(v0.x);
    acc[1] += bfhi(v0.x);
    acc[2] += bflo(v0.y);
    acc[3] += bfhi(v0.y);
    acc[4] += bflo(v0.z);
    acc[5] += bfhi(v0.z);
    acc[6] += bflo(v0.w);
    acc[7] += bfhi(v0.w);
  }
  int deg = r1 - r0;
  float rd = 1.0f / (float)(deg > 0 ? deg : 1);
  if (ACC) {
    float4* dp = reinterpret_cast<float4*>(dstf + (size_t)n * 64 + j * 8);
    float4 p0 = dp[0], p1 = dp[1];
    p0.x += acc[0] * rd; p0.y += acc[1] * rd;
    p0.z += acc[2] * rd; p0.w += acc[3] * rd;
    p1.x += acc[4] * rd; p1.y += acc[5] * rd;
    p1.z += acc[6] * rd; p1.w += acc[7] * rd;
    dp[0] = p0; dp[1] = p1;
  } else {
    uint4 o;
    o.x = (unsigned)f2bf(acc[0] * rd) | ((unsigned)f2bf(acc[1] * rd) << 16);
    o.y = (unsigned)f2bf(acc[2] * rd) | ((unsigned)f2bf(acc[3] * rd) << 16);
    o.z = (unsigned)f2bf(acc[4] * rd) | ((unsigned)f2bf(acc[5] * rd) << 16);
    o.w = (unsigned)f2bf(acc[6] * rd) | ((unsigned)f2bf(acc[7] * rd) << 16);
    *reinterpret_cast<uint4*>(dstb + (size_t)n * 64 + j * 8) = o;
  }
}

// ---------------------------------------------------------------------------
// gemm1_mfma: hb[N x 128] (bf16) = [xb | aggxb] @ [Ws1 ; Wn1] + b1
// A rows already bf16 -> A-load is one 16B load. W transposed + XOR-swizzled
// in LDS. C/D: col = lane&15, row = (lane>>4)*4 + reg.
// ---------------------------------------------------------------------------
__global__ __launch_bounds__(256) void gemm1_mfma(
    const unsigned short* __restrict__ xb,
    const unsigned short* __restrict__ aggxb, const float* __restrict__ Ws,
    const float* __restrict__ Wn, const float* __restrict__ b,
    unsigned short* __restrict__ hb) {
  __shared__ __align__(16) unsigned short wt[128 * 128];  // [col][k], swizzled
  __shared__ float bs[HID];
  int tid = threadIdx.x;
  for (int i = tid; i < 128 * 128; i += 256) {
    int k = i >> 7, j = i & 127;
    float v = (k < 64) ? Ws[k * HID + j] : Wn[(k - 64) * HID + j];
    int idx = (j << 7) | k;
    wt[idx ^ ((j & 15) << 3)] = f2bf(v);
  }
  if (tid < HID) bs[tid] = b[tid];
  __syncthreads();

  int wave = tid >> 6, lane = tid & 63;
  int m = lane & 15, kg = lane >> 4;
  int rbase = blockIdx.x * 64 + wave * 16;
  int rowa = rbase + m;
  if (rowa >= N_NODES) rowa = N_NODES - 1;  // clamp (stores guarded)

  short8v a[4];
#pragma unroll
  for (int kt = 0; kt < 4; ++kt) {
    int c0 = kt * 32 + kg * 8;
    const unsigned short* src = (c0 < 64)
                                    ? (xb + (size_t)rowa * 64 + c0)
                                    : (aggxb + (size_t)rowa * 64 + (c0 - 64));
    a[kt] = *reinterpret_cast<const short8v*>(src);
  }

  f32x4 acc[8];
#pragma unroll
  for (int nt = 0; nt < 8; ++nt) acc[nt] = (f32x4){0.f, 0.f, 0.f, 0.f};

#pragma unroll
  for (int nt = 0; nt < 8; ++nt) {
    int col = nt * 16 + m;
    int base = col << 7;
    int sw = (col & 15) << 3;
#pragma unroll
    for (int kt = 0; kt < 4; ++kt) {
      int idx = (base | (kt * 32 + kg * 8)) ^ sw;
      short8v bf = *reinterpret_cast<const short8v*>(&wt[idx]);
      acc[nt] = __builtin_amdgcn_mfma_f32_16x16x32_bf16(a[kt], bf, acc[nt], 0, 0, 0);
    }
  }

#pragma unroll
  for (int nt = 0; nt < 8; ++nt) {
    int col = nt * 16 + m;
    float bias = bs[col];
#pragma unroll
    for (int r = 0; r < 4; ++r) {
      int rr = rbase + kg * 4 + r;
      if (rr < N_NODES) hb[(size_t)rr * HID + col] = f2bf(acc[nt][r] + bias);
    }
  }
}

// ---------------------------------------------------------------------------
// bnstats: per-feature sum / sumsq over nodes (bf16 h)
// ---------------------------------------------------------------------------
__global__ __launch_bounds__(256) void bnstats_kernel(
    const unsigned short* __restrict__ hb, float* __restrict__ bnsum) {
  int f = threadIdx.x & 127;
  int half = threadIdx.x >> 7;
  int stride = gridDim.x * 2;
  float s = 0.f, q = 0.f;
  for (int r = blockIdx.x * 2 + half; r < N_NODES; r += stride) {
    float v = __uint_as_float((unsigned)hb[(size_t)r * HID + f] << 16);
    s += v;
    q += v * v;
  }
  __shared__ float ls[256];
  __shared__ float lq[256];
  ls[threadIdx.x] = s;
  lq[threadIdx.x] = q;
  __syncthreads();
  if (half == 0) {
    unsafeAtomicAdd(bnsum + f, ls[f] + ls[f + 128]);
    unsafeAtomicAdd(bnsum + 128 + f, lq[f] + lq[f + 128]);
  }
}

__global__ void bnfinal_kernel(const float* __restrict__ bnsum,
                               const float* __restrict__ gamma,
                               const float* __restrict__ beta,
                               float* __restrict__ scale,
                               float* __restrict__ shift) {
  int f = threadIdx.x;
  if (f >= HID) return;
  const float invn = 1.0f / (float)N_NODES;
  float mu = bnsum[f] * invn;
  float var = bnsum[128 + f] * invn - mu * mu;
  float sc = gamma[f] * rsqrtf(var + BN_EPS);
  scale[f] = sc;
  shift[f] = beta[f] - mu * sc;
}

// ---------------------------------------------------------------------------
// gemm2_mfma: hbn = relu(bn(hb)); [z | s] = hbn @ [Wn2 | Ws2].
// z -> zb (bf16), s + b2 -> out (fp32). BN+ReLU fused in A-load.
// ---------------------------------------------------------------------------
__global__ __launch_bounds__(256) void gemm2_mfma(
    const unsigned short* __restrict__ hb, const float* __restrict__ scale,
    const float* __restrict__ shift, const float* __restrict__ Wn,
    const float* __restrict__ Ws, const float* __restrict__ b,
    unsigned short* __restrict__ zb, float* __restrict__ out) {
  __shared__ __align__(16) unsigned short wt[128 * 128];  // [col][k], swizzled
  __shared__ float scs[HID];
  __shared__ float shs[HID];
  __shared__ float bz[OUT_F];
  int tid = threadIdx.x;
  for (int i = tid; i < 128 * 128; i += 256) {
    int k = i >> 7, j = i & 127;
    float v = (j < 64) ? Wn[k * OUT_F + j] : Ws[k * OUT_F + (j - 64)];
    int idx = (j << 7) | k;
    wt[idx ^ ((j & 15) << 3)] = f2bf(v);
  }
  if (tid < HID) {
    scs[tid] = scale[tid];
    shs[tid] = shift[tid];
  }
  if (tid < OUT_F) bz[tid] = b[tid];
  __syncthreads();

  int wave = tid >> 6, lane = tid & 63;
  int m = lane & 15, kg = lane >> 4;
  int rbase = blockIdx.x * 64 + wave * 16;
  int rowa = rbase + m;
  if (rowa >= N_NODES) rowa = N_NODES - 1;

  short8v a[4];
#pragma unroll
  for (int kt = 0; kt < 4; ++kt) {
    int c0 = kt * 32 + kg * 8;
    uint4 raw = *reinterpret_cast<const uint4*>(hb + (size_t)rowa * HID + c0);
    float4 sc0 = *reinterpret_cast<const float4*>(&scs[c0]);
    float4 sc1 = *reinterpret_cast<const float4*>(&scs[c0 + 4]);
    float4 sh0 = *reinterpret_cast<const float4*>(&shs[c0]);
    float4 sh1 = *reinterpret_cast<const float4*>(&shs[c0 + 4]);
    short8v av;
    av[0] = (short)f2bf(fmaxf(bflo(raw.x) * sc0.x + sh0.x, 0.f));
    av[1] = (short)f2bf(fmaxf(bfhi(raw.x) * sc0.y + sh0.y, 0.f));
    av[2] = (short)f2bf(fmaxf(bflo(raw.y) * sc0.z + sh0.z, 0.f));
    av[3] = (short)f2bf(fmaxf(bfhi(raw.y) * sc0.w + sh0.w, 0.f));
    av[4] = (short)f2bf(fmaxf(bflo(raw.z) * sc1.x + sh1.x, 0.f));
    av[5] = (short)f2bf(fmaxf(bfhi(raw.z) * sc1.y + sh1.y, 0.f));
    av[6] = (short)f2bf(fmaxf(bflo(raw.w) * sc1.z + sh1.z, 0.f));
    av[7] = (short)f2bf(fmaxf(bfhi(raw.w) * sc1.w + sh1.w, 0.f));
    a[kt] = av;
  }

  f32x4 acc[8];
#pragma unroll
  for (int nt = 0; nt < 8; ++nt) acc[nt] = (f32x4){0.f, 0.f, 0.f, 0.f};

#pragma unroll
  for (int nt = 0; nt < 8; ++nt) {
    int col = nt * 16 + m;
    int base = col << 7;
    int sw = (col & 15) << 3;
#pragma unroll
    for (int kt = 0; kt < 4; ++kt) {
      int idx = (base | (kt * 32 + kg * 8)) ^ sw;
      short8v bf = *reinterpret_cast<const short8v*>(&wt[idx]);
      acc[nt] = __builtin_amdgcn_mfma_f32_16x16x32_bf16(a[kt], bf, acc[nt], 0, 0, 0);
    }
  }

#pragma unroll
  for (int nt = 0; nt < 8; ++nt) {
    int col = nt * 16 + m;
#pragma unroll
    for (int r = 0; r < 4; ++r) {
      int rr = rbase + kg * 4 + r;
      if (rr < N_NODES) {
        float v = acc[nt][r];
        if (col < 64)
          zb[(size_t)rr * OUT_F + col] = f2bf(v);
        else
          out[(size_t)rr * OUT_F + (col - 64)] = v + bz[col - 64];
      }
    }
  }
}

// ---------------------------------------------------------------------------
extern "C" void kernel_launch(void* const* d_in, const int* in_sizes, int n_in,
                              void* d_out, int out_size, void* d_ws,
                              size_t ws_size, hipStream_t stream) {
  const float* x = (const float*)d_in[0];
  const int* esrc = (const int*)d_in[1];
  const int* edst = (const int*)d_in[2];
  const float* Ws1 = (const float*)d_in[3];
  const float* Wn1 = (const float*)d_in[4];
  const float* b1 = (const float*)d_in[5];
  const float* gamma = (const float*)d_in[6];
  const float* beta = (const float*)d_in[7];
  const float* Ws2 = (const float*)d_in[8];
  const float* Wn2 = (const float*)d_in[9];
  const float* b2 = (const float*)d_in[10];
  float* out = (float*)d_out;

  float* ws = (float*)d_ws;
  float* bnsum = ws;                         // 256
  float* bnscale = ws + 256;                 // 128
  float* bnshift = ws + 384;                 // 128
  int* cursor = (int*)(ws + 512);            // N (degrees after pass1)
  int* rowstart = cursor + N_NODES;          // N+1
  int* bsum = rowstart + N_NODES + 1;        // SCAN_NBLK
  int* boff = bsum + SCAN_NBLK;              // SCAN_NBLK
  int* csr = boff + SCAN_NBLK;               // E  (4B aligned)
  int pos16_off = ((512 + 2 * N_NODES + 1 + 2 * SCAN_NBLK + N_EDGES) + 3) & ~3;
  unsigned short* pos16 = (unsigned short*)(ws + pos16_off);       // E ushort
  unsigned short* xb = (unsigned short*)(ws + pos16_off + N_EDGES / 2);
  unsigned short* aggxb = xb + (size_t)N_NODES * 64;               // also zb
  unsigned short* hb = aggxb + (size_t)N_NODES * 64;               // N*128

  const int e4grid = (N_EDGES / 4 + 255) / 256;
  zero_kernel<<<(N_NODES / 4 + 255) / 256, 256, 0, stream>>>(cursor);
  cvt_kernel<<<(N_NODES * IN_F / 8 + 255) / 256, 256, 0, stream>>>(x, xb);
  pass1_kernel<<<e4grid, 256, 0, stream>>>(edst, cursor, pos16);
  blocksum_kernel<<<SCAN_NBLK, 256, 0, stream>>>(cursor, bsum);
  scanb_kernel<<<1, 512, 0, stream>>>(bsum, boff, rowstart, bnsum);
  writerow_kernel<<<SCAN_NBLK, 256, 0, stream>>>(cursor, boff, rowstart);
  scatter_kernel<<<e4grid, 256, 0, stream>>>(esrc, edst, pos16, rowstart, csr);

  const int ggrid = (N_NODES + 63) / 64;
  const int agrid = (N_NODES + 31) / 32;
  // layer 1: aggxb = mean_in(xb); hb = [xb|aggxb] @ [Ws1;Wn1] + b1
  aggb_kernel<false><<<agrid, 256, 0, stream>>>(xb, rowstart, csr, aggxb,
                                                nullptr);
  gemm1_mfma<<<ggrid, 256, 0, stream>>>(xb, aggxb, Ws1, Wn1, b1, hb);

  // batchnorm stats
  bnstats_kernel<<<1024, 256, 0, stream>>>(hb, bnsum);
  bnfinal_kernel<<<1, 128, 0, stream>>>(bnsum, gamma, beta, bnscale, bnshift);

  // layer 2: [zb|s] = relu(bn(hb)) @ [Wn2|Ws2]; out = s + b2; out += mean(zb)
  gemm2_mfma<<<ggrid, 256, 0, stream>>>(hb, bnscale, bnshift, Wn2, Ws2, b2,
                                        aggxb, out);
  aggb_kernel<true><<<agrid, 256, 0, stream>>>(aggxb, rowstart, csr, nullptr,
                                               out);
}

// Round 11
// 179.616 us; speedup vs baseline: 12.9647x; 1.2354x over previous
//
#include <hip/hip_runtime.h>

#define N_NODES 100000
#define N_EDGES 800000
#define IN_F 64
#define HID 128
#define OUT_F 64
#define BN_EPS 1e-5f
#define SCAN_NBLK ((N_NODES + 255) / 256)  // 391

typedef __attribute__((ext_vector_type(8))) short short8v;
typedef __attribute__((ext_vector_type(4))) float f32x4;

static __device__ __forceinline__ unsigned short f2bf(float f) {
  unsigned u = __float_as_uint(f);
  return (unsigned short)((u + 0x7FFFu + ((u >> 16) & 1u)) >> 16);
}
static __device__ __forceinline__ float bflo(unsigned u) {
  return __uint_as_float(u << 16);
}
static __device__ __forceinline__ float bfhi(unsigned u) {
  return __uint_as_float(u & 0xFFFF0000u);
}

// ---------------------------------------------------------------------------
// cvtzero: xb = bf16(x) (8 elems/thread) + zero cursor (first 25000 threads)
// ---------------------------------------------------------------------------
__global__ __launch_bounds__(256) void cvtzero_kernel(
    const float* __restrict__ x, unsigned short* __restrict__ xb,
    int* __restrict__ cursor) {
  int t = blockIdx.x * 256 + threadIdx.x;
  if (t < N_NODES / 4) {  // 25000 int4 = 100000 ints exactly
    int4 z = {0, 0, 0, 0};
    reinterpret_cast<int4*>(cursor)[t] = z;
  }
  if (t >= N_NODES * IN_F / 8) return;
  float4 a = reinterpret_cast<const float4*>(x)[t * 2];
  float4 b = reinterpret_cast<const float4*>(x)[t * 2 + 1];
  uint4 o;
  o.x = (unsigned)f2bf(a.x) | ((unsigned)f2bf(a.y) << 16);
  o.y = (unsigned)f2bf(a.z) | ((unsigned)f2bf(a.w) << 16);
  o.z = (unsigned)f2bf(b.x) | ((unsigned)f2bf(b.y) << 16);
  o.w = (unsigned)f2bf(b.z) | ((unsigned)f2bf(b.w) << 16);
  reinterpret_cast<uint4*>(xb)[t] = o;
}

// ---------------------------------------------------------------------------
// pass1: pos16[e] = cursor[dst]++  (atomic pass gives rank AND histogram)
// ---------------------------------------------------------------------------
__global__ __launch_bounds__(256) void pass1_kernel(
    const int* __restrict__ edst, int* __restrict__ cursor,
    unsigned short* __restrict__ pos16) {
  int t = blockIdx.x * 256 + threadIdx.x;
  if (t >= N_EDGES / 4) return;
  int4 d = reinterpret_cast<const int4*>(edst)[t];
  ushort4 p;
  p.x = (unsigned short)atomicAdd(cursor + d.x, 1);
  p.y = (unsigned short)atomicAdd(cursor + d.y, 1);
  p.z = (unsigned short)atomicAdd(cursor + d.z, 1);
  p.w = (unsigned short)atomicAdd(cursor + d.w, 1);
  reinterpret_cast<ushort4*>(pos16)[t] = p;
}

// ---------------------------------------------------------------------------
// hierarchical scan over cursor (= degrees): blocksum -> scanb -> writerow
// ---------------------------------------------------------------------------
__global__ __launch_bounds__(256) void blocksum_kernel(
    const int* __restrict__ degi, int* __restrict__ bsum) {
  __shared__ int ls[256];
  int i = blockIdx.x * 256 + threadIdx.x;
  ls[threadIdx.x] = (i < N_NODES) ? degi[i] : 0;
  __syncthreads();
  for (int off = 128; off > 0; off >>= 1) {
    if (threadIdx.x < off) ls[threadIdx.x] += ls[threadIdx.x + off];
    __syncthreads();
  }
  if (threadIdx.x == 0) bsum[blockIdx.x] = ls[0];
}

// also zeroes bnsum (used later by bnstats) to avoid a memset dispatch
__global__ __launch_bounds__(512) void scanb_kernel(
    const int* __restrict__ bsum, int* __restrict__ boff,
    int* __restrict__ rowstart, float* __restrict__ bnsum) {
  __shared__ int ls[512];
  int t = threadIdx.x;
  if (t < 256) bnsum[t] = 0.f;
  int v = (t < SCAN_NBLK) ? bsum[t] : 0;
  ls[t] = v;
  __syncthreads();
  for (int off = 1; off < 512; off <<= 1) {
    int u = (t >= off) ? ls[t - off] : 0;
    __syncthreads();
    ls[t] += u;
    __syncthreads();
  }
  if (t < SCAN_NBLK) boff[t] = ls[t] - v;  // exclusive
  if (t == 511) rowstart[N_NODES] = ls[511];
}

__global__ __launch_bounds__(256) void writerow_kernel(
    const int* __restrict__ degi, const int* __restrict__ boff,
    int* __restrict__ rowstart) {
  __shared__ int ls[256];
  int i = blockIdx.x * 256 + threadIdx.x;
  int t = threadIdx.x;
  int v = (i < N_NODES) ? degi[i] : 0;
  ls[t] = v;
  __syncthreads();
  for (int off = 1; off < 256; off <<= 1) {
    int u = (t >= off) ? ls[t - off] : 0;
    __syncthreads();
    ls[t] += u;
    __syncthreads();
  }
  if (i < N_NODES) rowstart[i] = boff[blockIdx.x] + ls[t] - v;
}

// ---------------------------------------------------------------------------
// scatter: csr[rowstart[dst] + pos16[e]] = src   (pure stores, no atomics)
// ---------------------------------------------------------------------------
__global__ __launch_bounds__(256) void scatter_kernel(
    const int* __restrict__ esrc, const int* __restrict__ edst,
    const unsigned short* __restrict__ pos16,
    const int* __restrict__ rowstart, int* __restrict__ csr) {
  int t = blockIdx.x * 256 + threadIdx.x;
  if (t >= N_EDGES / 4) return;
  int4 s = reinterpret_cast<const int4*>(esrc)[t];
  int4 d = reinterpret_cast<const int4*>(edst)[t];
  ushort4 p = reinterpret_cast<const ushort4*>(pos16)[t];
  csr[rowstart[d.x] + p.x] = s.x;
  csr[rowstart[d.y] + p.y] = s.y;
  csr[rowstart[d.z] + p.z] = s.z;
  csr[rowstart[d.w] + p.w] = s.w;
}

// ---------------------------------------------------------------------------
// aggb1: dstb[n] = bf16(mean of bf16 feat rows [N][64] over in-edges)
// 8 lanes/node, 16B per lane; fp32 accumulate.
// ---------------------------------------------------------------------------
__global__ __launch_bounds__(256) void aggb1_kernel(
    const unsigned short* __restrict__ featb, const int* __restrict__ rowstart,
    const int* __restrict__ csr, unsigned short* __restrict__ dstb) {
  int n = blockIdx.x * 32 + (threadIdx.x >> 3);
  int j = threadIdx.x & 7;
  if (n >= N_NODES) return;
  int r0 = rowstart[n];
  int r1 = rowstart[n + 1];
  float acc[8] = {0.f, 0.f, 0.f, 0.f, 0.f, 0.f, 0.f, 0.f};
  int i = r0;
  for (; i + 1 < r1; i += 2) {
    int s0 = csr[i];
    int s1 = csr[i + 1];
    uint4 v0 = *reinterpret_cast<const uint4*>(featb + (size_t)s0 * 64 + j * 8);
    uint4 v1 = *reinterpret_cast<const uint4*>(featb + (size_t)s1 * 64 + j * 8);
    acc[0] += bflo(v0.x) + bflo(v1.x);
    acc[1] += bfhi(v0.x) + bfhi(v1.x);
    acc[2] += bflo(v0.y) + bflo(v1.y);
    acc[3] += bfhi(v0.y) + bfhi(v1.y);
    acc[4] += bflo(v0.z) + bflo(v1.z);
    acc[5] += bfhi(v0.z) + bfhi(v1.z);
    acc[6] += bflo(v0.w) + bflo(v1.w);
    acc[7] += bfhi(v0.w) + bfhi(v1.w);
  }
  if (i < r1) {
    int s0 = csr[i];
    uint4 v0 = *reinterpret_cast<const uint4*>(featb + (size_t)s0 * 64 + j * 8);
    acc[0] += bflo(v0.x);
    acc[1] += bfhi(v0.x);
    acc[2] += bflo(v0.y);
    acc[3] += bfhi(v0.y);
    acc[4] += bflo(v0.z);
    acc[5] += bfhi(v0.z);
    acc[6] += bflo(v0.w);
    acc[7] += bfhi(v0.w);
  }
  int deg = r1 - r0;
  float rd = 1.0f / (float)(deg > 0 ? deg : 1);
  uint4 o;
  o.x = (unsigned)f2bf(acc[0] * rd) | ((unsigned)f2bf(acc[1] * rd) << 16);
  o.y = (unsigned)f2bf(acc[2] * rd) | ((unsigned)f2bf(acc[3] * rd) << 16);
  o.z = (unsigned)f2bf(acc[4] * rd) | ((unsigned)f2bf(acc[5] * rd) << 16);
  o.w = (unsigned)f2bf(acc[6] * rd) | ((unsigned)f2bf(acc[7] * rd) << 16);
  *reinterpret_cast<uint4*>(dstb + (size_t)n * 64 + j * 8) = o;
}

// ---------------------------------------------------------------------------
// aggb2: out[n] = bf16_s[n] + mean(zb over in-edges)   (write-once fp32 out)
// ---------------------------------------------------------------------------
__global__ __launch_bounds__(256) void aggb2_kernel(
    const unsigned short* __restrict__ zb, const unsigned short* __restrict__ sb,
    const int* __restrict__ rowstart, const int* __restrict__ csr,
    float* __restrict__ out) {
  int n = blockIdx.x * 32 + (threadIdx.x >> 3);
  int j = threadIdx.x & 7;
  if (n >= N_NODES) return;
  int r0 = rowstart[n];
  int r1 = rowstart[n + 1];
  float acc[8] = {0.f, 0.f, 0.f, 0.f, 0.f, 0.f, 0.f, 0.f};
  int i = r0;
  for (; i + 1 < r1; i += 2) {
    int s0 = csr[i];
    int s1 = csr[i + 1];
    uint4 v0 = *reinterpret_cast<const uint4*>(zb + (size_t)s0 * 64 + j * 8);
    uint4 v1 = *reinterpret_cast<const uint4*>(zb + (size_t)s1 * 64 + j * 8);
    acc[0] += bflo(v0.x) + bflo(v1.x);
    acc[1] += bfhi(v0.x) + bfhi(v1.x);
    acc[2] += bflo(v0.y) + bflo(v1.y);
    acc[3] += bfhi(v0.y) + bfhi(v1.y);
    acc[4] += bflo(v0.z) + bflo(v1.z);
    acc[5] += bfhi(v0.z) + bfhi(v1.z);
    acc[6] += bflo(v0.w) + bflo(v1.w);
    acc[7] += bfhi(v0.w) + bfhi(v1.w);
  }
  if (i < r1) {
    int s0 = csr[i];
    uint4 v0 = *reinterpret_cast<const uint4*>(zb + (size_t)s0 * 64 + j * 8);
    acc[0] += bflo(v0.x);
    acc[1] += bfhi(v0.x);
    acc[2] += bflo(v0.y);
    acc[3] += bfhi(v0.y);
    acc[4] += bflo(v0.z);
    acc[5] += bfhi(v0.z);
    acc[6] += bflo(v0.w);
    acc[7] += bfhi(v0.w);
  }
  int deg = r1 - r0;
  float rd = 1.0f / (float)(deg > 0 ? deg : 1);
  uint4 sv = *reinterpret_cast<const uint4*>(sb + (size_t)n * 64 + j * 8);
  float4 o0, o1;
  o0.x = bflo(sv.x) + acc[0] * rd;
  o0.y = bfhi(sv.x) + acc[1] * rd;
  o0.z = bflo(sv.y) + acc[2] * rd;
  o0.w = bfhi(sv.y) + acc[3] * rd;
  o1.x = bflo(sv.z) + acc[4] * rd;
  o1.y = bfhi(sv.z) + acc[5] * rd;
  o1.z = bflo(sv.w) + acc[6] * rd;
  o1.w = bfhi(sv.w) + acc[7] * rd;
  float4* dp = reinterpret_cast<float4*>(out + (size_t)n * 64 + j * 8);
  dp[0] = o0;
  dp[1] = o1;
}

// ---------------------------------------------------------------------------
// gemm1_mfma: hb[N x 128] (bf16) = [xb | aggxb] @ [Ws1 ; Wn1] + b1
// 8 waves, 128 rows/block. W transposed + XOR-swizzled in LDS.
// ---------------------------------------------------------------------------
__global__ __launch_bounds__(512) void gemm1_mfma(
    const unsigned short* __restrict__ xb,
    const unsigned short* __restrict__ aggxb, const float* __restrict__ Ws,
    const float* __restrict__ Wn, const float* __restrict__ b,
    unsigned short* __restrict__ hb) {
  __shared__ __align__(16) unsigned short wt[128 * 128];  // [col][k], swizzled
  __shared__ float bs[HID];
  int tid = threadIdx.x;
  for (int i = tid; i < 128 * 128; i += 512) {
    int k = i >> 7, j = i & 127;
    float v = (k < 64) ? Ws[k * HID + j] : Wn[(k - 64) * HID + j];
    int idx = (j << 7) | k;
    wt[idx ^ ((j & 15) << 3)] = f2bf(v);
  }
  if (tid < HID) bs[tid] = b[tid];
  __syncthreads();

  int wave = tid >> 6, lane = tid & 63;
  int m = lane & 15, kg = lane >> 4;
  int rbase = blockIdx.x * 128 + wave * 16;
  int rowa = rbase + m;
  if (rowa >= N_NODES) rowa = N_NODES - 1;  // clamp (stores guarded)

  short8v a[4];
#pragma unroll
  for (int kt = 0; kt < 4; ++kt) {
    int c0 = kt * 32 + kg * 8;
    const unsigned short* src = (c0 < 64)
                                    ? (xb + (size_t)rowa * 64 + c0)
                                    : (aggxb + (size_t)rowa * 64 + (c0 - 64));
    a[kt] = *reinterpret_cast<const short8v*>(src);
  }

  f32x4 acc[8];
#pragma unroll
  for (int nt = 0; nt < 8; ++nt) acc[nt] = (f32x4){0.f, 0.f, 0.f, 0.f};

#pragma unroll
  for (int nt = 0; nt < 8; ++nt) {
    int col = nt * 16 + m;
    int base = col << 7;
    int sw = (col & 15) << 3;
#pragma unroll
    for (int kt = 0; kt < 4; ++kt) {
      int idx = (base | (kt * 32 + kg * 8)) ^ sw;
      short8v bf = *reinterpret_cast<const short8v*>(&wt[idx]);
      acc[nt] = __builtin_amdgcn_mfma_f32_16x16x32_bf16(a[kt], bf, acc[nt], 0, 0, 0);
    }
  }

#pragma unroll
  for (int nt = 0; nt < 8; ++nt) {
    int col = nt * 16 + m;
    float bias = bs[col];
#pragma unroll
    for (int r = 0; r < 4; ++r) {
      int rr = rbase + kg * 4 + r;
      if (rr < N_NODES) hb[(size_t)rr * HID + col] = f2bf(acc[nt][r] + bias);
    }
  }
}

// ---------------------------------------------------------------------------
// bnstats: per-feature sum/sumsq over nodes, uint4-vectorized.
// 16 lanes/row (8 feats each), 16 rows in flight per block.
// ---------------------------------------------------------------------------
__global__ __launch_bounds__(256) void bnstats_kernel(
    const unsigned short* __restrict__ hb, float* __restrict__ bnsum) {
  int j = threadIdx.x & 15;   // feature block (8 feats)
  int g = threadIdx.x >> 4;   // row group 0..15
  float s[8] = {0.f, 0.f, 0.f, 0.f, 0.f, 0.f, 0.f, 0.f};
  float q[8] = {0.f, 0.f, 0.f, 0.f, 0.f, 0.f, 0.f, 0.f};
  for (int r = blockIdx.x * 16 + g; r < N_NODES; r += gridDim.x * 16) {
    uint4 v = *reinterpret_cast<const uint4*>(hb + (size_t)r * HID + j * 8);
    float f0 = bflo(v.x), f1 = bfhi(v.x), f2 = bflo(v.y), f3 = bfhi(v.y);
    float f4 = bflo(v.z), f5 = bfhi(v.z), f6 = bflo(v.w), f7 = bfhi(v.w);
    s[0] += f0; q[0] += f0 * f0;
    s[1] += f1; q[1] += f1 * f1;
    s[2] += f2; q[2] += f2 * f2;
    s[3] += f3; q[3] += f3 * f3;
    s[4] += f4; q[4] += f4 * f4;
    s[5] += f5; q[5] += f5 * f5;
    s[6] += f6; q[6] += f6 * f6;
    s[7] += f7; q[7] += f7 * f7;
  }
  __shared__ float lss[256 * 8];
  __shared__ float lqq[256 * 8];
#pragma unroll
  for (int e = 0; e < 8; ++e) {
    lss[threadIdx.x * 8 + e] = s[e];
    lqq[threadIdx.x * 8 + e] = q[e];
  }
  __syncthreads();
  if (threadIdx.x < 128) {
    int f = threadIdx.x;
    int jj = f >> 3, e = f & 7;
    float S = 0.f, Q = 0.f;
#pragma unroll
    for (int gg = 0; gg < 16; ++gg) {
      S += lss[(gg * 16 + jj) * 8 + e];
      Q += lqq[(gg * 16 + jj) * 8 + e];
    }
    unsafeAtomicAdd(bnsum + f, S);
    unsafeAtomicAdd(bnsum + 128 + f, Q);
  }
}

// ---------------------------------------------------------------------------
// gemm2_mfma: computes scale/shift from bnsum inline (bnfinal folded);
// hbn = relu(bn(hb)); [z | s] = hbn @ [Wn2 | Ws2]; zb bf16, sb = s+b2 bf16.
// 8 waves, 128 rows/block.
// ---------------------------------------------------------------------------
__global__ __launch_bounds__(512) void gemm2_mfma(
    const unsigned short* __restrict__ hb, const float* __restrict__ bnsum,
    const float* __restrict__ gamma, const float* __restrict__ beta,
    const float* __restrict__ Wn, const float* __restrict__ Ws,
    const float* __restrict__ b, unsigned short* __restrict__ zb,
    unsigned short* __restrict__ sb) {
  __shared__ __align__(16) unsigned short wt[128 * 128];  // [col][k], swizzled
  __shared__ float scs[HID];
  __shared__ float shs[HID];
  __shared__ float bz[OUT_F];
  int tid = threadIdx.x;
  for (int i = tid; i < 128 * 128; i += 512) {
    int k = i >> 7, j = i & 127;
    float v = (j < 64) ? Wn[k * OUT_F + j] : Ws[k * OUT_F + (j - 64)];
    int idx = (j << 7) | k;
    wt[idx ^ ((j & 15) << 3)] = f2bf(v);
  }
  if (tid < HID) {  // bnfinal inline
    const float invn = 1.0f / (float)N_NODES;
    float mu = bnsum[tid] * invn;
    float var = bnsum[128 + tid] * invn - mu * mu;
    float sc = gamma[tid] * rsqrtf(var + BN_EPS);
    scs[tid] = sc;
    shs[tid] = beta[tid] - mu * sc;
  }
  if (tid < OUT_F) bz[tid] = b[tid];
  __syncthreads();

  int wave = tid >> 6, lane = tid & 63;
  int m = lane & 15, kg = lane >> 4;
  int rbase = blockIdx.x * 128 + wave * 16;
  int rowa = rbase + m;
  if (rowa >= N_NODES) rowa = N_NODES - 1;

  short8v a[4];
#pragma unroll
  for (int kt = 0; kt < 4; ++kt) {
    int c0 = kt * 32 + kg * 8;
    uint4 raw = *reinterpret_cast<const uint4*>(hb + (size_t)rowa * HID + c0);
    float4 sc0 = *reinterpret_cast<const float4*>(&scs[c0]);
    float4 sc1 = *reinterpret_cast<const float4*>(&scs[c0 + 4]);
    float4 sh0 = *reinterpret_cast<const float4*>(&shs[c0]);
    float4 sh1 = *reinterpret_cast<const float4*>(&shs[c0 + 4]);
    short8v av;
    av[0] = (short)f2bf(fmaxf(bflo(raw.x) * sc0.x + sh0.x, 0.f));
    av[1] = (short)f2bf(fmaxf(bfhi(raw.x) * sc0.y + sh0.y, 0.f));
    av[2] = (short)f2bf(fmaxf(bflo(raw.y) * sc0.z + sh0.z, 0.f));
    av[3] = (short)f2bf(fmaxf(bfhi(raw.y) * sc0.w + sh0.w, 0.f));
    av[4] = (short)f2bf(fmaxf(bflo(raw.z) * sc1.x + sh1.x, 0.f));
    av[5] = (short)f2bf(fmaxf(bfhi(raw.z) * sc1.y + sh1.y, 0.f));
    av[6] = (short)f2bf(fmaxf(bflo(raw.w) * sc1.z + sh1.z, 0.f));
    av[7] = (short)f2bf(fmaxf(bfhi(raw.w) * sc1.w + sh1.w, 0.f));
    a[kt] = av;
  }

  f32x4 acc[8];
#pragma unroll
  for (int nt = 0; nt < 8; ++nt) acc[nt] = (f32x4){0.f, 0.f, 0.f, 0.f};

#pragma unroll
  for (int nt = 0; nt < 8; ++nt) {
    int col = nt * 16 + m;
    int base = col << 7;
    int sw = (col & 15) << 3;
#pragma unroll
    for (int kt = 0; kt < 4; ++kt) {
      int idx = (base | (kt * 32 + kg * 8)) ^ sw;
      short8v bf = *reinterpret_cast<const short8v*>(&wt[idx]);
      acc[nt] = __builtin_amdgcn_mfma_f32_16x16x32_bf16(a[kt], bf, acc[nt], 0, 0, 0);
    }
  }

#pragma unroll
  for (int nt = 0; nt < 8; ++nt) {
    int col = nt * 16 + m;
#pragma unroll
    for (int r = 0; r < 4; ++r) {
      int rr = rbase + kg * 4 + r;
      if (rr < N_NODES) {
        float v = acc[nt][r];
        if (col < 64)
          zb[(size_t)rr * OUT_F + col] = f2bf(v);
        else
          sb[(size_t)rr * OUT_F + (col - 64)] = f2bf(v + bz[col - 64]);
      }
    }
  }
}

// ---------------------------------------------------------------------------
extern "C" void kernel_launch(void* const* d_in, const int* in_sizes, int n_in,
                              void* d_out, int out_size, void* d_ws,
                              size_t ws_size, hipStream_t stream) {
  const float* x = (const float*)d_in[0];
  const int* esrc = (const int*)d_in[1];
  const int* edst = (const int*)d_in[2];
  const float* Ws1 = (const float*)d_in[3];
  const float* Wn1 = (const float*)d_in[4];
  const float* b1 = (const float*)d_in[5];
  const float* gamma = (const float*)d_in[6];
  const float* beta = (const float*)d_in[7];
  const float* Ws2 = (const float*)d_in[8];
  const float* Wn2 = (const float*)d_in[9];
  const float* b2 = (const float*)d_in[10];
  float* out = (float*)d_out;

  float* ws = (float*)d_ws;
  float* bnsum = ws;                         // 256
  int* cursor = (int*)(ws + 512);            // N (degrees after pass1)
  int* rowstart = cursor + N_NODES;          // N+1
  int* bsum = rowstart + N_NODES + 1;        // SCAN_NBLK
  int* boff = bsum + SCAN_NBLK;              // SCAN_NBLK
  int* csr = boff + SCAN_NBLK;               // E
  int pos16_off = ((512 + 2 * N_NODES + 1 + 2 * SCAN_NBLK + N_EDGES) + 3) & ~3;
  unsigned short* pos16 = (unsigned short*)(ws + pos16_off);        // E ushort
  unsigned short* xb = (unsigned short*)(ws + pos16_off + N_EDGES / 2);
  unsigned short* aggxb = xb + (size_t)N_NODES * 64;                // also zb
  unsigned short* sb = aggxb + (size_t)N_NODES * 64;                // N*64
  unsigned short* hb = sb + (size_t)N_NODES * 64;                   // N*128

  const int e4grid = (N_EDGES / 4 + 255) / 256;
  cvtzero_kernel<<<(N_NODES * IN_F / 8 + 255) / 256, 256, 0, stream>>>(x, xb,
                                                                       cursor);
  pass1_kernel<<<e4grid, 256, 0, stream>>>(edst, cursor, pos16);
  blocksum_kernel<<<SCAN_NBLK, 256, 0, stream>>>(cursor, bsum);
  scanb_kernel<<<1, 512, 0, stream>>>(bsum, boff, rowstart, bnsum);
  writerow_kernel<<<SCAN_NBLK, 256, 0, stream>>>(cursor, boff, rowstart);
  scatter_kernel<<<e4grid, 256, 0, stream>>>(esrc, edst, pos16, rowstart, csr);

  const int ggrid = (N_NODES + 127) / 128;
  const int agrid = (N_NODES + 31) / 32;
  // layer 1: aggxb = mean_in(xb); hb = [xb|aggxb] @ [Ws1;Wn1] + b1
  aggb1_kernel<<<agrid, 256, 0, stream>>>(xb, rowstart, csr, aggxb);
  gemm1_mfma<<<ggrid, 512, 0, stream>>>(xb, aggxb, Ws1, Wn1, b1, hb);

  // batchnorm stats (finalize folded into gemm2 prologue)
  bnstats_kernel<<<256, 256, 0, stream>>>(hb, bnsum);

  // layer 2: [zb|sb] = relu(bn(hb)) @ [Wn2|Ws2]; out = sb + mean_in(zb)
  gemm2_mfma<<<ggrid, 512, 0, stream>>>(hb, bnsum, gamma, beta, Wn2, Ws2, b2,
                                        aggxb, sb);
  aggb2_kernel<<<agrid, 256, 0, stream>>>(aggxb, sb, rowstart, csr, out);
}